// Round 2
// baseline (1447.960 us; speedup 1.0000x reference)
//
#include <hip/hip_runtime.h>
#include <hip/hip_bf16.h>
#include <stdint.h>

// Problem constants (fixed by reference setup)
#define NATOMS 16384          // B*NPB = 512*32
#define ETOT   327680         // NATOMS*K (K=20 neighbors)
#define EQ     81920          // edge quarter (node-aligned: 81920 % 20 == 0)
#define NQ     4096           // nodes per quarter
#define NLAYER 4

typedef __hip_bfloat16 bf16;
using bf16x8 = __attribute__((ext_vector_type(8))) short;   // MFMA A/B frag (4 VGPRs)
using f32x4  = __attribute__((ext_vector_type(4))) float;   // MFMA C/D frag

// ---------------------------------------------------------------------------
// async global->LDS 16B (direct-to-LDS DMA; dest = wave-uniform base + lane*16)
// ---------------------------------------------------------------------------
__device__ __forceinline__ void async16(const void* g, void* l) {
  __builtin_amdgcn_global_load_lds(
      (const __attribute__((address_space(1))) unsigned int*)g,
      (__attribute__((address_space(3))) unsigned int*)l, 16, 0, 0);
}

// ---------------------------------------------------------------------------
// Tiled bf16 MFMA GEMM: C[128 x 256] per block, 4 waves, K in chunks of 64.
//  A: [M][KTOT] bf16 row-major (for KTOT=512: rows are [A | A2], 256 each)
//  B: [Ncols][KTOT] bf16  (W^T, n-major) -> contiguous k-octets per n
// LDS swizzle: octet (r, ko) lives at 16B-slot f = r*8 + (ko ^ (r&7)); the
// global source address is permuted so the LDS image stays a linear
// global_load_lds target.
// Epilogues:
//  0: store bf16 at ldOut (h @ [We1_r|We1_c] -> Prc)
//  2: += bias, relu, store bf16 (edge MLP2 in-place / node MLP1 in-place)
//  4: += bias; h = 2*h + val; store h f32 + bf16 (node MLP2 + residuals)
// ---------------------------------------------------------------------------
template<int KTOT, int EPI>
__global__ void __launch_bounds__(256, 2)
gemm_k(const bf16* A, const bf16* A2, const bf16* B,
       bf16* Obf, int ldOut, const float* bias,
       float* Hf, bf16* Hbf)
{
  __shared__ __align__(16) char smem[49152];   // A tile 16KB @0, B tile 32KB @16384
  __shared__ float s_bias[256];

  const int tid  = threadIdx.x;
  const int w    = tid >> 6;        // wave 0..3 (owns 64-col slice)
  const int lane = tid & 63;
  const int q    = lane >> 4;       // quad
  const int t16  = lane & 15;
  const size_t row0 = (size_t)blockIdx.x * 128;
  const int ncol0 = blockIdx.y * 256;

  if constexpr (EPI == 2 || EPI == 4) s_bias[tid] = bias[tid];

  f32x4 acc[8][4] = {};   // [mi][ni], 128 VGPRs

  constexpr int NCHUNK = KTOT / 64;
  for (int kc = 0; kc < NCHUNK; ++kc) {
    const int k0 = kc * 64;
    const bf16* Asrc; int k0e; int ldA;
    if constexpr (KTOT == 512) {            // node MLP1: concat [h | agg]
      if (k0 < 256) { Asrc = A;  k0e = k0;       }
      else          { Asrc = A2; k0e = k0 - 256; }
      ldA = 256;
    } else {
      Asrc = A; k0e = k0; ldA = KTOT;
    }

    __syncthreads();                         // previous chunk's LDS reads done
    // stage A tile [128][64] = 16 issues of 1KB (4 per wave)
    #pragma unroll
    for (int ii = 0; ii < 4; ++ii) {
      int i = w * 4 + ii;
      int f = i * 64 + lane;                 // 16B slot index
      int m = f >> 3, s = f & 7;
      int ko = s ^ (m & 7);                  // which global k-octet goes here
      const bf16* g = Asrc + (row0 + (size_t)m) * ldA + (size_t)(k0e + ko * 8);
      async16(g, smem + i * 1024);
    }
    // stage B tile [256 n][64 k] = 32 issues (8 per wave)
    #pragma unroll
    for (int ii = 0; ii < 8; ++ii) {
      int i = w * 8 + ii;
      int f = i * 64 + lane;
      int n = f >> 3, s = f & 7;
      int ko = s ^ (n & 7);
      const bf16* g = B + (size_t)(ncol0 + n) * KTOT + (size_t)(k0 + ko * 8);
      async16(g, smem + 16384 + i * 1024);
    }
    __syncthreads();                         // drains vmcnt before barrier

    #pragma unroll
    for (int ks = 0; ks < 2; ++ks) {
      bf16x8 av[8]; bf16x8 bv[4];
      const int ko = q + 4 * ks;             // operand: k = ko*8 + j
      #pragma unroll
      for (int mi = 0; mi < 8; ++mi) {       // A: m = lane&15, k = quad*8+j
        int m = 16 * mi + t16;
        int f = m * 8 + (ko ^ (m & 7));
        av[mi] = *(const bf16x8*)(smem + f * 16);
      }
      #pragma unroll
      for (int ni = 0; ni < 4; ++ni) {       // B: n = lane&15, k = quad*8+j
        int n = 64 * w + 16 * ni + t16;
        int f = n * 8 + (ko ^ (n & 7));
        bv[ni] = *(const bf16x8*)(smem + 16384 + f * 16);
      }
      #pragma unroll
      for (int mi = 0; mi < 8; ++mi)
        #pragma unroll
        for (int ni = 0; ni < 4; ++ni)
          acc[mi][ni] = __builtin_amdgcn_mfma_f32_16x16x32_bf16(
              av[mi], bv[ni], acc[mi][ni], 0, 0, 0);
    }
  }

  // epilogue: C/D layout col = lane&15, row = quad*4 + reg  [m89-verified]
  #pragma unroll
  for (int mi = 0; mi < 8; ++mi) {
    #pragma unroll
    for (int ni = 0; ni < 4; ++ni) {
      #pragma unroll
      for (int r = 0; r < 4; ++r) {
        int rl = 16 * mi + 4 * q + r;
        int cl = 64 * w + 16 * ni + t16;
        size_t rg = row0 + rl;
        float val = acc[mi][ni][r];
        if constexpr (EPI == 0) {
          Obf[rg * ldOut + (ncol0 + cl)] = __float2bfloat16(val);
        } else if constexpr (EPI == 2) {
          val = fmaxf(val + s_bias[cl], 0.f);
          Obf[rg * 256 + cl] = __float2bfloat16(val);
        } else {  // EPI == 4: h_new = 2*h + (acc + bias)
          val += s_bias[cl];
          float hn = 2.f * Hf[rg * 256 + cl] + val;
          Hf[rg * 256 + cl]  = hn;
          Hbf[rg * 256 + cl] = __float2bfloat16(hn);
        }
      }
    }
  }
}

// ---------------------------------------------------------------------------
// Edge MLP1 (fused): per block 128 edges. Computes dist/radial from pos+eidx,
// builds the Gaussian A-tile [128][64] directly in LDS (no global eattr),
// stages WgT via async16, one K=64 MFMA pass, epilogue adds
// P_r[row]+P_c[col]+radial*w_rad+bias, relu, writes quarter-local m.
// ---------------------------------------------------------------------------
__global__ void __launch_bounds__(256, 2)
gemm_edge1(const bf16* WgT_l, const float* off, const float* pos,
           const int* eidx, int e0, const bf16* Prc,
           const float* bias, const float* wrad, bf16* Om)
{
  __shared__ __align__(16) char smem[49152];
  __shared__ int   s_erow[128];
  __shared__ int   s_ecol[128];
  __shared__ float s_rad[128];
  __shared__ float s_dist[128];
  __shared__ float s_bias[256];
  __shared__ float s_wrad[256];
  __shared__ float s_off[64];

  const int tid  = threadIdx.x;
  const int w    = tid >> 6;
  const int lane = tid & 63;
  const int q    = lane >> 4;
  const int t16  = lane & 15;
  const int erow0 = e0 + blockIdx.x * 128;   // global edge base of this block

  if (tid < 128) {
    int e = erow0 + tid;
    int r = eidx[e], c = eidx[ETOT + e];
    float dx = pos[c * 3 + 0] - pos[r * 3 + 0];
    float dy = pos[c * 3 + 1] - pos[r * 3 + 1];
    float dz = pos[c * 3 + 2] - pos[r * 3 + 2];
    float d2 = dx * dx + dy * dy + dz * dz;
    s_erow[tid] = r; s_ecol[tid] = c;
    s_rad[tid]  = 0.01f * d2;                // (ANG_TO_NM)^2 * |dvec|^2
    s_dist[tid] = sqrtf(d2);
  }
  if (tid < 64) s_off[tid] = off[tid];
  s_bias[tid] = bias[tid];
  s_wrad[tid] = wrad[tid];

  // stage B tile [256 n][64 k] (WgT) via async DMA — no dependence on s_*
  #pragma unroll
  for (int ii = 0; ii < 8; ++ii) {
    int i = w * 8 + ii;
    int f = i * 64 + lane;
    int n = f >> 3, s = f & 7;
    int ko = s ^ (n & 7);
    async16(WgT_l + (size_t)n * 64 + ko * 8, smem + 16384 + i * 1024);
  }
  __syncthreads();                           // s_dist/s_off ready

  // Gaussian A tile [128 m][64 k] -> LDS with swizzle, 4 x ds_write_b128/thread
  {
    const float GC = -0.5f / ((5.0f / 63.0f) * (5.0f / 63.0f));
    int m = tid >> 1, half = tid & 1;
    float d = s_dist[m];
    #pragma unroll
    for (int ko2 = 0; ko2 < 4; ++ko2) {
      int ko = half * 4 + ko2;
      bf16x8 v;
      #pragma unroll
      for (int j = 0; j < 8; ++j) {
        float t = d - s_off[ko * 8 + j];
        bf16 b = __float2bfloat16(__expf(GC * t * t));
        v[j] = *(short*)&b;
      }
      int f = m * 8 + (ko ^ (m & 7));
      *(bf16x8*)(smem + f * 16) = v;
    }
  }
  __syncthreads();                           // drains lgkmcnt (A) + vmcnt (B)

  f32x4 acc[8][4] = {};
  #pragma unroll
  for (int ks = 0; ks < 2; ++ks) {
    bf16x8 av[8]; bf16x8 bv[4];
    const int ko = q + 4 * ks;
    #pragma unroll
    for (int mi = 0; mi < 8; ++mi) {
      int m = 16 * mi + t16;
      int f = m * 8 + (ko ^ (m & 7));
      av[mi] = *(const bf16x8*)(smem + f * 16);
    }
    #pragma unroll
    for (int ni = 0; ni < 4; ++ni) {
      int n = 64 * w + 16 * ni + t16;
      int f = n * 8 + (ko ^ (n & 7));
      bv[ni] = *(const bf16x8*)(smem + 16384 + f * 16);
    }
    #pragma unroll
    for (int mi = 0; mi < 8; ++mi)
      #pragma unroll
      for (int ni = 0; ni < 4; ++ni)
        acc[mi][ni] = __builtin_amdgcn_mfma_f32_16x16x32_bf16(
            av[mi], bv[ni], acc[mi][ni], 0, 0, 0);
  }

  #pragma unroll
  for (int mi = 0; mi < 8; ++mi) {
    #pragma unroll
    for (int ni = 0; ni < 4; ++ni) {
      #pragma unroll
      for (int r = 0; r < 4; ++r) {
        int rl = 16 * mi + 4 * q + r;
        int cl = 64 * w + 16 * ni + t16;
        float val = acc[mi][ni][r];
        val += s_bias[cl] + s_rad[rl] * s_wrad[cl];
        val += __bfloat162float(Prc[(size_t)s_erow[rl] * 512 + cl]);        // P_r
        val += __bfloat162float(Prc[(size_t)s_ecol[rl] * 512 + 256 + cl]);  // P_c
        val = fmaxf(val, 0.f);
        Om[((size_t)blockIdx.x * 128 + rl) * 256 + cl] = __float2bfloat16(val);
      }
    }
  }
}

// ---------------------------------------------------------------------------
// Prep kernels: weight repack/transpose to bf16 [n][k] layouts, once per call
// ---------------------------------------------------------------------------
__global__ void wrct_kernel(const float* We1, bf16* WrcT) {
  int idx = blockIdx.x * 256 + threadIdx.x;         // L*512*256
  int k = idx & 255, np = (idx >> 8) & 511, l = idx >> 17;
  float v = (np < 256)
      ? We1[((size_t)l * 577 + k) * 256 + np]
      : We1[((size_t)l * 577 + 256 + k) * 256 + (np - 256)];
  WrcT[idx] = __float2bfloat16(v);
}
__global__ void wgt_kernel(const float* We1, bf16* WgT) {
  int idx = blockIdx.x * 256 + threadIdx.x;         // L*256*64
  int k = idx & 63, n = (idx >> 6) & 255, l = idx >> 14;
  WgT[idx] = __float2bfloat16(We1[((size_t)l * 577 + 513 + k) * 256 + n]);
}
__global__ void wrad_kernel(const float* We1, float* wrad) {
  int idx = blockIdx.x * 256 + threadIdx.x;         // L*256
  int n = idx & 255, l = idx >> 8;
  wrad[idx] = We1[((size_t)l * 577 + 512) * 256 + n];
}
__global__ void trans_kernel(const float* src, bf16* dst, int R, int C) {
  int idx = blockIdx.x * 256 + threadIdx.x;         // L*C*R, dst [l][n][k]
  int k = idx % R, rest = idx / R;
  int n = rest % C, l = rest / C;
  dst[idx] = __float2bfloat16(src[((size_t)l * R + k) * C + n]);
}

__global__ void h0_kernel(const int* types, const float* emb, float* h, bf16* hbf) {
  int i = blockIdx.x, c = threadIdx.x;
  float v = emb[(size_t)(types[i] - 1) * 256 + c];
  h[(size_t)i * 256 + c] = v;
  hbf[(size_t)i * 256 + c] = __float2bfloat16(v);
}

// segment-sum over one quarter: node-local, exactly 20 row-sorted edges/node
__global__ void agg_q_kernel(const bf16* mq, bf16* aggbf, int v0) {
  int vl = blockIdx.x, c = threadIdx.x;
  const bf16* p = mq + (size_t)vl * 20 * 256 + c;
  float s = 0.f;
  #pragma unroll
  for (int j = 0; j < 20; ++j) s += __bfloat162float(p[j * 256]);
  aggbf[(size_t)(v0 + vl) * 256 + c] = __float2bfloat16(s);
}

// global mean pool over 32 atoms per building block
__global__ void pool_kernel(const float* h, float* out) {
  int b = blockIdx.x, c = threadIdx.x;
  float s = 0.f;
  #pragma unroll
  for (int j = 0; j < 32; ++j) s += h[((size_t)b * 32 + j) * 256 + c];
  out[(size_t)b * 256 + c] = s * (1.0f / 32.0f);
}

// ---------------------------------------------------------------------------
extern "C" void kernel_launch(void* const* d_in, const int* in_sizes, int n_in,
                              void* d_out, int out_size, void* d_ws, size_t ws_size,
                              hipStream_t stream) {
  const float* pos   = (const float*)d_in[0];
  const int*   atype = (const int*)  d_in[1];
  const int*   eidx  = (const int*)  d_in[2];
  const float* emb   = (const float*)d_in[4];
  const float* off   = (const float*)d_in[5];
  const float* We1   = (const float*)d_in[6];
  const float* be1   = (const float*)d_in[7];
  const float* We2   = (const float*)d_in[8];
  const float* be2   = (const float*)d_in[9];
  const float* Wn1   = (const float*)d_in[10];
  const float* bn1   = (const float*)d_in[11];
  const float* Wn2   = (const float*)d_in[12];
  const float* bn2   = (const float*)d_in[13];
  float* out = (float*)d_out;

  // ---- workspace carve (256B aligned, ~96 MB total) ----
  size_t o = 0;
  auto carve = [&](size_t bytes) {
    void* p = (char*)d_ws + o;
    o += (bytes + 255) & ~(size_t)255;
    return p;
  };
  float* h     = (float*)carve((size_t)NATOMS * 256 * 4);   // 16 MB
  bf16*  hbf   = (bf16*) carve((size_t)NATOMS * 256 * 2);   //  8 MB
  bf16*  Prc   = (bf16*) carve((size_t)NATOMS * 512 * 2);   // 16 MB
  bf16*  mq    = (bf16*) carve((size_t)EQ * 256 * 2);       // 40 MB (edge quarter)
  bf16*  aggbf = (bf16*) carve((size_t)NATOMS * 256 * 2);   //  8 MB (agg, then node-MLP1 out)
  bf16*  WrcT  = (bf16*) carve((size_t)NLAYER * 512 * 256 * 2);
  bf16*  WgT   = (bf16*) carve((size_t)NLAYER * 256 * 64 * 2);
  bf16*  We2T  = (bf16*) carve((size_t)NLAYER * 256 * 256 * 2);
  bf16*  Wn1T  = (bf16*) carve((size_t)NLAYER * 256 * 512 * 2);
  bf16*  Wn2T  = (bf16*) carve((size_t)NLAYER * 256 * 256 * 2);
  float* wradp = (float*)carve((size_t)NLAYER * 256 * 4);

  // ---- prep: weights -> bf16 transposed, h0 gather ----
  wrct_kernel<<<2048, 256, 0, stream>>>(We1, WrcT);
  wgt_kernel <<< 256, 256, 0, stream>>>(We1, WgT);
  wrad_kernel<<<   4, 256, 0, stream>>>(We1, wradp);
  trans_kernel<<<1024, 256, 0, stream>>>(We2, We2T, 256, 256);
  trans_kernel<<<2048, 256, 0, stream>>>(Wn1, Wn1T, 512, 256);
  trans_kernel<<<1024, 256, 0, stream>>>(Wn2, Wn2T, 256, 256);
  h0_kernel  <<<NATOMS, 256, 0, stream>>>(atype, emb, h, hbf);

  // ---- layers ----
  for (int l = 0; l < NLAYER; ++l) {
    // Prc[N,512] = h @ [We1_r | We1_c]
    gemm_k<256, 0><<<dim3(128, 2), 256, 0, stream>>>(
        hbf, nullptr, WrcT + (size_t)l * 512 * 256, Prc, 512, nullptr,
        nullptr, nullptr);
    // edge pipeline in 4 node-aligned quarters (m buffer = 40 MB not 160 MB)
    for (int qtr = 0; qtr < 4; ++qtr) {
      gemm_edge1<<<EQ / 128, 256, 0, stream>>>(
          WgT + (size_t)l * 256 * 64, off, pos, eidx, qtr * EQ, Prc,
          be1 + l * 256, wradp + l * 256, mq);
      gemm_k<256, 2><<<dim3(EQ / 128, 1), 256, 0, stream>>>(
          mq, nullptr, We2T + (size_t)l * 256 * 256, mq, 256, be2 + l * 256,
          nullptr, nullptr);
      agg_q_kernel<<<NQ, 256, 0, stream>>>(mq, aggbf, qtr * NQ);
    }
    // t[N,256] = relu([h|agg] @ Wn1 + bn1), in-place into aggbf
    gemm_k<512, 2><<<dim3(128, 1), 256, 0, stream>>>(
        hbf, aggbf, Wn1T + (size_t)l * 256 * 512, aggbf, 256, bn1 + l * 256,
        nullptr, nullptr);
    // h = 2h + (t @ Wn2 + bn2)
    gemm_k<256, 4><<<dim3(128, 1), 256, 0, stream>>>(
        aggbf, nullptr, Wn2T + (size_t)l * 256 * 256, nullptr, 0, bn2 + l * 256,
        h, hbf);
  }

  pool_kernel<<<512, 256, 0, stream>>>(h, out);
}

// Round 3
// 1151.669 us; speedup vs baseline: 1.2573x; 1.2573x over previous
//
#include <hip/hip_runtime.h>
#include <hip/hip_bf16.h>
#include <stdint.h>

// Problem constants (fixed by reference setup)
#define NATOMS 16384          // B*NPB = 512*32
#define ETOT   327680         // NATOMS*K (K=20 neighbors)
#define NLAYER 4

typedef __hip_bfloat16 bf16;
using bf16x8 = __attribute__((ext_vector_type(8))) short;   // MFMA A/B frag (4 VGPRs)
using f32x4  = __attribute__((ext_vector_type(4))) float;   // MFMA C/D frag

// ---------------------------------------------------------------------------
// async global->LDS 16B (direct-to-LDS DMA; dest = wave-uniform base + lane*16)
// ---------------------------------------------------------------------------
__device__ __forceinline__ void async16(const void* g, void* l) {
  __builtin_amdgcn_global_load_lds(
      (const __attribute__((address_space(1))) unsigned int*)g,
      (__attribute__((address_space(3))) unsigned int*)l, 16, 0, 0);
}

// ---------------------------------------------------------------------------
// Tiled bf16 MFMA GEMM: C[MT x 256] per block, 4 waves (64 cols each),
// K in chunks of 64.  MT in {64,128}.
//  A: [M][KTOT] bf16 row-major (KTOT=512: rows are [A | A2], 256 each)
//  B: [Ncols][KTOT] bf16  (W^T, n-major) -> contiguous k-octets per n
// LDS swizzle: octet (r, ko) lives at 16B-slot f = r*8 + (ko ^ (r&7)); the
// global source address is permuted so the LDS image stays a linear
// global_load_lds target.
// Epilogues:
//  0: store bf16 at ldOut (h @ [We1_r|We1_c] -> Prc)
//  2: += bias, relu, store bf16 (edge MLP2 in-place / node MLP1 in-place)
//  4: += bias; h = 2*h + val; store h f32 + bf16 (node MLP2 + residuals)
// In-place (EPI 2) is safe: a block reads only its own A rows across all K
// before its epilogue writes those same rows.
// ---------------------------------------------------------------------------
template<int KTOT, int EPI, int MT>
__global__ void __launch_bounds__(256, 2)
gemm_k(const bf16* A, const bf16* A2, const bf16* B,
       bf16* Obf, int ldOut, const float* bias,
       float* Hf, bf16* Hbf)
{
  __shared__ __align__(16) char smem[49152];   // A tile @0 (<=16KB), B tile 32KB @16384
  __shared__ float s_bias[256];

  const int tid  = threadIdx.x;
  const int w    = tid >> 6;        // wave 0..3 (owns 64-col slice)
  const int lane = tid & 63;
  const int q    = lane >> 4;       // quad
  const int t16  = lane & 15;
  const size_t row0 = (size_t)blockIdx.x * MT;
  const int ncol0 = blockIdx.y * 256;
  constexpr int MI = MT / 16;       // row-tiles per wave
  constexpr int AI = MT / 32;       // A-stage issues per wave (MT/8 total /4)

  if constexpr (EPI == 2 || EPI == 4) s_bias[tid] = bias[tid];

  f32x4 acc[MI][4] = {};

  constexpr int NCHUNK = KTOT / 64;
  for (int kc = 0; kc < NCHUNK; ++kc) {
    const int k0 = kc * 64;
    const bf16* Asrc; int k0e; int ldA;
    if constexpr (KTOT == 512) {            // node MLP1: concat [h | agg]
      if (k0 < 256) { Asrc = A;  k0e = k0;       }
      else          { Asrc = A2; k0e = k0 - 256; }
      ldA = 256;
    } else {
      Asrc = A; k0e = k0; ldA = KTOT;
    }

    __syncthreads();                         // previous chunk's LDS reads done
    // stage A tile [MT][64]
    #pragma unroll
    for (int ii = 0; ii < AI; ++ii) {
      int i = w * AI + ii;
      int f = i * 64 + lane;                 // 16B slot index
      int m = f >> 3, s = f & 7;
      int ko = s ^ (m & 7);                  // which global k-octet goes here
      const bf16* g = Asrc + (row0 + (size_t)m) * ldA + (size_t)(k0e + ko * 8);
      async16(g, smem + i * 1024);
    }
    // stage B tile [256 n][64 k] = 32 issues (8 per wave)
    #pragma unroll
    for (int ii = 0; ii < 8; ++ii) {
      int i = w * 8 + ii;
      int f = i * 64 + lane;
      int n = f >> 3, s = f & 7;
      int ko = s ^ (n & 7);
      const bf16* g = B + (size_t)(ncol0 + n) * KTOT + (size_t)(k0 + ko * 8);
      async16(g, smem + 16384 + i * 1024);
    }
    __syncthreads();                         // drains vmcnt before barrier

    #pragma unroll
    for (int ks = 0; ks < 2; ++ks) {
      bf16x8 av[MI]; bf16x8 bv[4];
      const int ko = q + 4 * ks;             // operand: k = ko*8 + j
      #pragma unroll
      for (int mi = 0; mi < MI; ++mi) {      // A: m = lane&15, k = quad*8+j
        int m = 16 * mi + t16;
        int f = m * 8 + (ko ^ (m & 7));
        av[mi] = *(const bf16x8*)(smem + f * 16);
      }
      #pragma unroll
      for (int ni = 0; ni < 4; ++ni) {       // B: n = lane&15, k = quad*8+j
        int n = 64 * w + 16 * ni + t16;
        int f = n * 8 + (ko ^ (n & 7));
        bv[ni] = *(const bf16x8*)(smem + 16384 + f * 16);
      }
      #pragma unroll
      for (int mi = 0; mi < MI; ++mi)
        #pragma unroll
        for (int ni = 0; ni < 4; ++ni)
          acc[mi][ni] = __builtin_amdgcn_mfma_f32_16x16x32_bf16(
              av[mi], bv[ni], acc[mi][ni], 0, 0, 0);
    }
  }

  // epilogue: C/D layout col = lane&15, row = quad*4 + reg  [m89-verified]
  #pragma unroll
  for (int mi = 0; mi < MI; ++mi) {
    #pragma unroll
    for (int ni = 0; ni < 4; ++ni) {
      #pragma unroll
      for (int r = 0; r < 4; ++r) {
        int rl = 16 * mi + 4 * q + r;
        int cl = 64 * w + 16 * ni + t16;
        size_t rg = row0 + rl;
        float val = acc[mi][ni][r];
        if constexpr (EPI == 0) {
          Obf[rg * ldOut + (ncol0 + cl)] = __float2bfloat16(val);
        } else if constexpr (EPI == 2) {
          val = fmaxf(val + s_bias[cl], 0.f);
          Obf[rg * 256 + cl] = __float2bfloat16(val);
        } else {  // EPI == 4: h_new = 2*h + (acc + bias)
          val += s_bias[cl];
          float hn = 2.f * Hf[rg * 256 + cl] + val;
          Hf[rg * 256 + cl]  = hn;
          Hbf[rg * 256 + cl] = __float2bfloat16(hn);
        }
      }
    }
  }
}

// ---------------------------------------------------------------------------
// Edge MLP1 (fused): per block 128 edges. Computes dist/radial from pos+eidx,
// builds the Gaussian A-tile [128][64] directly in LDS (no global eattr),
// stages WgT via async16, one K=64 MFMA pass, epilogue adds
// P_r[row]+P_c[col]+radial*w_rad+bias, relu, writes m.
// ---------------------------------------------------------------------------
__global__ void __launch_bounds__(256, 2)
gemm_edge1(const bf16* WgT_l, const float* off, const float* pos,
           const int* eidx, const bf16* Prc,
           const float* bias, const float* wrad, bf16* Om)
{
  __shared__ __align__(16) char smem[49152];
  __shared__ int   s_erow[128];
  __shared__ int   s_ecol[128];
  __shared__ float s_rad[128];
  __shared__ float s_dist[128];
  __shared__ float s_bias[256];
  __shared__ float s_wrad[256];
  __shared__ float s_off[64];

  const int tid  = threadIdx.x;
  const int w    = tid >> 6;
  const int lane = tid & 63;
  const int q    = lane >> 4;
  const int t16  = lane & 15;
  const int erow0 = blockIdx.x * 128;        // global edge base of this block

  if (tid < 128) {
    int e = erow0 + tid;
    int r = eidx[e], c = eidx[ETOT + e];
    float dx = pos[c * 3 + 0] - pos[r * 3 + 0];
    float dy = pos[c * 3 + 1] - pos[r * 3 + 1];
    float dz = pos[c * 3 + 2] - pos[r * 3 + 2];
    float d2 = dx * dx + dy * dy + dz * dz;
    s_erow[tid] = r; s_ecol[tid] = c;
    s_rad[tid]  = 0.01f * d2;                // (ANG_TO_NM)^2 * |dvec|^2
    s_dist[tid] = sqrtf(d2);
  }
  if (tid < 64) s_off[tid] = off[tid];
  s_bias[tid] = bias[tid];
  s_wrad[tid] = wrad[tid];

  // stage B tile [256 n][64 k] (WgT) via async DMA — no dependence on s_*
  #pragma unroll
  for (int ii = 0; ii < 8; ++ii) {
    int i = w * 8 + ii;
    int f = i * 64 + lane;
    int n = f >> 3, s = f & 7;
    int ko = s ^ (n & 7);
    async16(WgT_l + (size_t)n * 64 + ko * 8, smem + 16384 + i * 1024);
  }
  __syncthreads();                           // s_dist/s_off ready

  // Gaussian A tile [128 m][64 k] -> LDS with swizzle, 4 x ds_write_b128/thread
  {
    const float GC = -0.5f / ((5.0f / 63.0f) * (5.0f / 63.0f));
    int m = tid >> 1, half = tid & 1;
    float d = s_dist[m];
    #pragma unroll
    for (int ko2 = 0; ko2 < 4; ++ko2) {
      int ko = half * 4 + ko2;
      bf16x8 v;
      #pragma unroll
      for (int j = 0; j < 8; ++j) {
        float t = d - s_off[ko * 8 + j];
        bf16 b = __float2bfloat16(__expf(GC * t * t));
        v[j] = *(short*)&b;
      }
      int f = m * 8 + (ko ^ (m & 7));
      *(bf16x8*)(smem + f * 16) = v;
    }
  }
  __syncthreads();                           // drains lgkmcnt (A) + vmcnt (B)

  f32x4 acc[8][4] = {};
  #pragma unroll
  for (int ks = 0; ks < 2; ++ks) {
    bf16x8 av[8]; bf16x8 bv[4];
    const int ko = q + 4 * ks;
    #pragma unroll
    for (int mi = 0; mi < 8; ++mi) {
      int m = 16 * mi + t16;
      int f = m * 8 + (ko ^ (m & 7));
      av[mi] = *(const bf16x8*)(smem + f * 16);
    }
    #pragma unroll
    for (int ni = 0; ni < 4; ++ni) {
      int n = 64 * w + 16 * ni + t16;
      int f = n * 8 + (ko ^ (n & 7));
      bv[ni] = *(const bf16x8*)(smem + 16384 + f * 16);
    }
    #pragma unroll
    for (int mi = 0; mi < 8; ++mi)
      #pragma unroll
      for (int ni = 0; ni < 4; ++ni)
        acc[mi][ni] = __builtin_amdgcn_mfma_f32_16x16x32_bf16(
            av[mi], bv[ni], acc[mi][ni], 0, 0, 0);
  }

  #pragma unroll
  for (int mi = 0; mi < 8; ++mi) {
    #pragma unroll
    for (int ni = 0; ni < 4; ++ni) {
      #pragma unroll
      for (int r = 0; r < 4; ++r) {
        int rl = 16 * mi + 4 * q + r;
        int cl = 64 * w + 16 * ni + t16;
        float val = acc[mi][ni][r];
        val += s_bias[cl] + s_rad[rl] * s_wrad[cl];
        val += __bfloat162float(Prc[(size_t)s_erow[rl] * 512 + cl]);        // P_r
        val += __bfloat162float(Prc[(size_t)s_ecol[rl] * 512 + 256 + cl]);  // P_c
        val = fmaxf(val, 0.f);
        Om[((size_t)erow0 + rl) * 256 + cl] = __float2bfloat16(val);
      }
    }
  }
}

// ---------------------------------------------------------------------------
// Prep kernels: weight repack/transpose to bf16 [n][k] layouts, once per call
// ---------------------------------------------------------------------------
__global__ void wrct_kernel(const float* We1, bf16* WrcT) {
  int idx = blockIdx.x * 256 + threadIdx.x;         // L*512*256
  int k = idx & 255, np = (idx >> 8) & 511, l = idx >> 17;
  float v = (np < 256)
      ? We1[((size_t)l * 577 + k) * 256 + np]
      : We1[((size_t)l * 577 + 256 + k) * 256 + (np - 256)];
  WrcT[idx] = __float2bfloat16(v);
}
__global__ void wgt_kernel(const float* We1, bf16* WgT) {
  int idx = blockIdx.x * 256 + threadIdx.x;         // L*256*64
  int k = idx & 63, n = (idx >> 6) & 255, l = idx >> 14;
  WgT[idx] = __float2bfloat16(We1[((size_t)l * 577 + 513 + k) * 256 + n]);
}
__global__ void wrad_kernel(const float* We1, float* wrad) {
  int idx = blockIdx.x * 256 + threadIdx.x;         // L*256
  int n = idx & 255, l = idx >> 8;
  wrad[idx] = We1[((size_t)l * 577 + 512) * 256 + n];
}
__global__ void trans_kernel(const float* src, bf16* dst, int R, int C) {
  int idx = blockIdx.x * 256 + threadIdx.x;         // L*C*R, dst [l][n][k]
  int k = idx % R, rest = idx / R;
  int n = rest % C, l = rest / C;
  dst[idx] = __float2bfloat16(src[((size_t)l * R + k) * C + n]);
}

__global__ void h0_kernel(const int* types, const float* emb, float* h, bf16* hbf) {
  int i = blockIdx.x, c = threadIdx.x;
  float v = emb[(size_t)(types[i] - 1) * 256 + c];
  h[(size_t)i * 256 + c] = v;
  hbf[(size_t)i * 256 + c] = __float2bfloat16(v);
}

// segment-sum: 20 row-sorted edges per node, vectorized 16B (8 ch / thread)
__global__ void __launch_bounds__(256)
agg_kernel(const bf16* m, bf16* aggbf) {
  int idx = blockIdx.x * 256 + threadIdx.x;   // NATOMS*32 threads
  int v = idx >> 5, c8 = (idx & 31) * 8;
  const bf16* p = m + (size_t)v * 20 * 256 + c8;
  float s[8] = {0.f, 0.f, 0.f, 0.f, 0.f, 0.f, 0.f, 0.f};
  #pragma unroll
  for (int j = 0; j < 20; ++j) {
    bf16x8 vv = *(const bf16x8*)(p + (size_t)j * 256);
    #pragma unroll
    for (int k = 0; k < 8; ++k) {
      short sv = vv[k];
      s[k] += __bfloat162float(*(bf16*)&sv);
    }
  }
  bf16x8 o;
  #pragma unroll
  for (int k = 0; k < 8; ++k) {
    bf16 b = __float2bfloat16(s[k]);
    o[k] = *(short*)&b;
  }
  *(bf16x8*)(aggbf + (size_t)v * 256 + c8) = o;
}

// global mean pool over 32 atoms per building block
__global__ void pool_kernel(const float* h, float* out) {
  int b = blockIdx.x, c = threadIdx.x;
  float s = 0.f;
  #pragma unroll
  for (int j = 0; j < 32; ++j) s += h[((size_t)b * 32 + j) * 256 + c];
  out[(size_t)b * 256 + c] = s * (1.0f / 32.0f);
}

// ---------------------------------------------------------------------------
extern "C" void kernel_launch(void* const* d_in, const int* in_sizes, int n_in,
                              void* d_out, int out_size, void* d_ws, size_t ws_size,
                              hipStream_t stream) {
  const float* pos   = (const float*)d_in[0];
  const int*   atype = (const int*)  d_in[1];
  const int*   eidx  = (const int*)  d_in[2];
  const float* emb   = (const float*)d_in[4];
  const float* off   = (const float*)d_in[5];
  const float* We1   = (const float*)d_in[6];
  const float* be1   = (const float*)d_in[7];
  const float* We2   = (const float*)d_in[8];
  const float* be2   = (const float*)d_in[9];
  const float* Wn1   = (const float*)d_in[10];
  const float* bn1   = (const float*)d_in[11];
  const float* Wn2   = (const float*)d_in[12];
  const float* bn2   = (const float*)d_in[13];
  float* out = (float*)d_out;

  // ---- workspace carve (256B aligned, ~221 MB total; ws_size = 256 MiB) ----
  size_t o = 0;
  auto carve = [&](size_t bytes) {
    void* p = (char*)d_ws + o;
    o += (bytes + 255) & ~(size_t)255;
    return p;
  };
  float* h     = (float*)carve((size_t)NATOMS * 256 * 4);   // 16 MB
  bf16*  hbf   = (bf16*) carve((size_t)NATOMS * 256 * 2);   //  8 MB
  bf16*  Prc   = (bf16*) carve((size_t)NATOMS * 512 * 2);   // 16 MB
  bf16*  m     = (bf16*) carve((size_t)ETOT * 256 * 2);     // 160 MB (MLP1->MLP2 in-place)
  bf16*  aggbf = (bf16*) carve((size_t)NATOMS * 256 * 2);   //  8 MB (agg, then nMLP1 out)
  bf16*  WrcT  = (bf16*) carve((size_t)NLAYER * 512 * 256 * 2);
  bf16*  WgT   = (bf16*) carve((size_t)NLAYER * 256 * 64 * 2);
  bf16*  We2T  = (bf16*) carve((size_t)NLAYER * 256 * 256 * 2);
  bf16*  Wn1T  = (bf16*) carve((size_t)NLAYER * 256 * 512 * 2);
  bf16*  Wn2T  = (bf16*) carve((size_t)NLAYER * 256 * 256 * 2);
  float* wradp = (float*)carve((size_t)NLAYER * 256 * 4);

  // ---- prep: weights -> bf16 transposed, h0 gather ----
  wrct_kernel<<<2048, 256, 0, stream>>>(We1, WrcT);
  wgt_kernel <<< 256, 256, 0, stream>>>(We1, WgT);
  wrad_kernel<<<   4, 256, 0, stream>>>(We1, wradp);
  trans_kernel<<<1024, 256, 0, stream>>>(We2, We2T, 256, 256);
  trans_kernel<<<2048, 256, 0, stream>>>(Wn1, Wn1T, 512, 256);
  trans_kernel<<<1024, 256, 0, stream>>>(Wn2, Wn2T, 256, 256);
  h0_kernel  <<<NATOMS, 256, 0, stream>>>(atype, emb, h, hbf);

  // ---- layers ----
  for (int l = 0; l < NLAYER; ++l) {
    // Prc[N,512] = h @ [We1_r | We1_c]   (64-row tiles -> 512 blocks)
    gemm_k<256, 0, 64><<<dim3(256, 2), 256, 0, stream>>>(
        hbf, nullptr, WrcT + (size_t)l * 512 * 256, Prc, 512, nullptr,
        nullptr, nullptr);
    // m[E,256] = relu(gauss(dist)@W_g + P_r[row] + P_c[col] + radial*w_rad + be1)
    gemm_edge1<<<ETOT / 128, 256, 0, stream>>>(
        WgT + (size_t)l * 256 * 64, off, pos, eidx, Prc,
        be1 + l * 256, wradp + l * 256, m);
    // m = relu(m @ We2 + be2), in-place
    gemm_k<256, 2, 128><<<dim3(ETOT / 128, 1), 256, 0, stream>>>(
        m, nullptr, We2T + (size_t)l * 256 * 256, m, 256, be2 + l * 256,
        nullptr, nullptr);
    // agg[N,256] = segment_sum (20 edges/node), 16B vectorized
    agg_kernel<<<NATOMS * 32 / 256, 256, 0, stream>>>(m, aggbf);
    // t[N,256] = relu([h|agg] @ Wn1 + bn1), in-place into aggbf
    gemm_k<512, 2, 64><<<dim3(256, 1), 256, 0, stream>>>(
        hbf, aggbf, Wn1T + (size_t)l * 256 * 512, aggbf, 256, bn1 + l * 256,
        nullptr, nullptr);
    // h = 2h + (t @ Wn2 + bn2)
    gemm_k<256, 4, 64><<<dim3(256, 1), 256, 0, stream>>>(
        aggbf, nullptr, Wn2T + (size_t)l * 256 * 256, nullptr, 0, bn2 + l * 256,
        h, hbf);
  }

  pool_kernel<<<512, 256, 0, stream>>>(h, out);
}

// Round 4
// 987.838 us; speedup vs baseline: 1.4658x; 1.1658x over previous
//
#include <hip/hip_runtime.h>
#include <hip/hip_bf16.h>
#include <stdint.h>

// Problem constants (fixed by reference setup)
#define NATOMS 16384          // B*NPB = 512*32
#define ETOT   327680         // NATOMS*K (K=20 neighbors)
#define NLAYER 4

typedef __hip_bfloat16 bf16;
using bf16x8 = __attribute__((ext_vector_type(8))) short;   // MFMA A/B frag (4 VGPRs)
using f32x4  = __attribute__((ext_vector_type(4))) float;   // MFMA C/D frag

#define LDSF_STRIDE 260   // f32 words per bridge row: 1040 B, 16B-aligned, 2-way banks

__device__ __forceinline__ float bf2f(short s) {
  union { float f; unsigned u; } x; x.u = ((unsigned)(unsigned short)s) << 16; return x.f;
}
__device__ __forceinline__ short f2bf(float f) {
  bf16 b = __float2bfloat16(f);
  return *(short*)&b;
}

// ---------------------------------------------------------------------------
// async global->LDS 16B (direct-to-LDS DMA; dest = wave-uniform base + lane*16)
// ---------------------------------------------------------------------------
__device__ __forceinline__ void async16(const void* g, void* l) {
  __builtin_amdgcn_global_load_lds(
      (const __attribute__((address_space(1))) unsigned int*)g,
      (__attribute__((address_space(3))) unsigned int*)l, 16, 0, 0);
}

// ---------------------------------------------------------------------------
// Tiled bf16 MFMA GEMM: C[MT x 256] per block, 4 waves (64 cols each),
// K in chunks of 64.  MT in {64,128}.
//  A: [M][KTOT] bf16 row-major (KTOT=512: rows are [A | A2], 256 each)
//  B: [Ncols][KTOT] bf16  (W^T, n-major) -> contiguous k-octets per n
// LDS swizzle: octet (r, ko) lives at 16B-slot f = r*8 + (ko ^ (r&7)); the
// global source address is permuted so the LDS image stays a linear
// global_load_lds target.
// Epilogue (all variants) goes through an LDS f32 transpose bridge so the
// final global stores are row-contiguous bf16x8 (one 512B segment per
// half-wave) instead of scalar 2B scatters.
//  0: store bf16 at ldOut (h @ [We1_r|We1_c] -> Prc)
//  2: += bias, relu, store bf16 (edge MLP2 in-place / node MLP1 in-place)
//  4: += bias; h = 2*h + val; store h f32 + bf16 (node MLP2 + residuals)
// In-place (EPI 2) is safe: a block reads only its own A rows across all K
// before its epilogue writes those same rows.
// ---------------------------------------------------------------------------
template<int KTOT, int EPI, int MT>
__global__ void __launch_bounds__(256, 2)
gemm_k(const bf16* A, const bf16* A2, const bf16* B,
       bf16* Obf, int ldOut, const float* bias,
       float* Hf, bf16* Hbf)
{
  __shared__ __align__(16) char smem[49152];   // A tile @0 (<=16KB), B tile 32KB @16384
  __shared__ float s_bias[256];

  const int tid  = threadIdx.x;
  const int w    = tid >> 6;        // wave 0..3 (owns 64-col slice)
  const int lane = tid & 63;
  const int q    = lane >> 4;       // quad
  const int t16  = lane & 15;
  const size_t row0 = (size_t)blockIdx.x * MT;
  const int ncol0 = blockIdx.y * 256;
  constexpr int MI = MT / 16;       // row-tiles per wave
  constexpr int AI = MT / 32;       // A-stage issues per wave (MT/8 total /4)

  if constexpr (EPI == 2 || EPI == 4) s_bias[tid] = bias[tid];

  f32x4 acc[MI][4] = {};

  constexpr int NCHUNK = KTOT / 64;
  for (int kc = 0; kc < NCHUNK; ++kc) {
    const int k0 = kc * 64;
    const bf16* Asrc; int k0e; int ldA;
    if constexpr (KTOT == 512) {            // node MLP1: concat [h | agg]
      if (k0 < 256) { Asrc = A;  k0e = k0;       }
      else          { Asrc = A2; k0e = k0 - 256; }
      ldA = 256;
    } else {
      Asrc = A; k0e = k0; ldA = KTOT;
    }

    __syncthreads();                         // previous chunk's LDS reads done
    // stage A tile [MT][64]
    #pragma unroll
    for (int ii = 0; ii < AI; ++ii) {
      int i = w * AI + ii;
      int f = i * 64 + lane;                 // 16B slot index
      int m = f >> 3, s = f & 7;
      int ko = s ^ (m & 7);                  // which global k-octet goes here
      const bf16* g = Asrc + (row0 + (size_t)m) * ldA + (size_t)(k0e + ko * 8);
      async16(g, smem + i * 1024);
    }
    // stage B tile [256 n][64 k] = 32 issues (8 per wave)
    #pragma unroll
    for (int ii = 0; ii < 8; ++ii) {
      int i = w * 8 + ii;
      int f = i * 64 + lane;
      int n = f >> 3, s = f & 7;
      int ko = s ^ (n & 7);
      const bf16* g = B + (size_t)(ncol0 + n) * KTOT + (size_t)(k0 + ko * 8);
      async16(g, smem + 16384 + i * 1024);
    }
    __syncthreads();                         // drains vmcnt before barrier

    #pragma unroll
    for (int ks = 0; ks < 2; ++ks) {
      bf16x8 av[MI]; bf16x8 bv[4];
      const int ko = q + 4 * ks;             // operand: k = ko*8 + j
      #pragma unroll
      for (int mi = 0; mi < MI; ++mi) {      // A: m = lane&15, k = quad*8+j
        int m = 16 * mi + t16;
        int f = m * 8 + (ko ^ (m & 7));
        av[mi] = *(const bf16x8*)(smem + f * 16);
      }
      #pragma unroll
      for (int ni = 0; ni < 4; ++ni) {       // B: n = lane&15, k = quad*8+j
        int n = 64 * w + 16 * ni + t16;
        int f = n * 8 + (ko ^ (n & 7));
        bv[ni] = *(const bf16x8*)(smem + 16384 + f * 16);
      }
      #pragma unroll
      for (int mi = 0; mi < MI; ++mi)
        #pragma unroll
        for (int ni = 0; ni < 4; ++ni)
          acc[mi][ni] = __builtin_amdgcn_mfma_f32_16x16x32_bf16(
              av[mi], bv[ni], acc[mi][ni], 0, 0, 0);
    }
  }

  // ---- epilogue via LDS transpose bridge ----
  // MFMA C/D layout: col = lane&15, row = quad*4 + reg  [m89-verified]
  float* lds_f = (float*)smem;               // [16][LDSF_STRIDE] chunk
  #pragma unroll
  for (int mi = 0; mi < MI; ++mi) {
    __syncthreads();                         // prev chunk consumed / K-loop reads done
    #pragma unroll
    for (int ni = 0; ni < 4; ++ni)
      #pragma unroll
      for (int r = 0; r < 4; ++r)
        lds_f[(4 * q + r) * LDSF_STRIDE + 64 * w + 16 * ni + t16] = acc[mi][ni][r];
    __syncthreads();
    #pragma unroll
    for (int j = 0; j < 2; ++j) {
      int task = tid + 256 * j;              // 512 tasks: 16 rows x 32 col-octets
      int rr = task >> 5, cg = task & 31;
      int c0 = cg * 8;
      size_t rg = row0 + 16 * mi + rr;
      f32x4 v0 = *(const f32x4*)(lds_f + rr * LDSF_STRIDE + c0);
      f32x4 v1 = *(const f32x4*)(lds_f + rr * LDSF_STRIDE + c0 + 4);
      float v[8] = {v0[0], v0[1], v0[2], v0[3], v1[0], v1[1], v1[2], v1[3]};
      if constexpr (EPI == 0) {
        bf16x8 o;
        #pragma unroll
        for (int k = 0; k < 8; ++k) o[k] = f2bf(v[k]);
        *(bf16x8*)(Obf + rg * ldOut + (ncol0 + c0)) = o;
      } else if constexpr (EPI == 2) {
        bf16x8 o;
        #pragma unroll
        for (int k = 0; k < 8; ++k) o[k] = f2bf(fmaxf(v[k] + s_bias[c0 + k], 0.f));
        *(bf16x8*)(Obf + rg * 256 + c0) = o;
      } else {  // EPI == 4: h_new = 2*h + (acc + bias)
        f32x4 h0 = *(const f32x4*)(Hf + rg * 256 + c0);
        f32x4 h1 = *(const f32x4*)(Hf + rg * 256 + c0 + 4);
        float hh[8] = {h0[0], h0[1], h0[2], h0[3], h1[0], h1[1], h1[2], h1[3]};
        bf16x8 o; f32x4 n0, n1;
        #pragma unroll
        for (int k = 0; k < 8; ++k) {
          float hn = 2.f * hh[k] + v[k] + s_bias[c0 + k];
          o[k] = f2bf(hn);
          if (k < 4) n0[k] = hn; else n1[k - 4] = hn;
        }
        *(f32x4*)(Hf + rg * 256 + c0)     = n0;
        *(f32x4*)(Hf + rg * 256 + c0 + 4) = n1;
        *(bf16x8*)(Hbf + rg * 256 + c0) = o;
      }
    }
  }
}

// ---------------------------------------------------------------------------
// Edge MLP1 (fused): per block 128 edges. Computes dist/radial from pos+eidx,
// builds the Gaussian A-tile [128][64] directly in LDS (no global eattr),
// stages WgT via async16, one K=64 MFMA pass. Epilogue goes through the LDS
// f32 bridge: each half-wave then handles one edge row with fully-coalesced
// 16B gathers of Prc[row], Prc[col] and a 16B store of m.
// ---------------------------------------------------------------------------
__global__ void __launch_bounds__(256, 2)
gemm_edge1(const bf16* WgT_l, const float* off, const float* pos,
           const int* eidx, const bf16* Prc,
           const float* bias, const float* wrad, bf16* Om)
{
  __shared__ __align__(16) char smem[49152];
  __shared__ int   s_erow[128];
  __shared__ int   s_ecol[128];
  __shared__ float s_rad[128];
  __shared__ float s_dist[128];
  __shared__ float s_bias[256];
  __shared__ float s_wrad[256];
  __shared__ float s_off[64];

  const int tid  = threadIdx.x;
  const int w    = tid >> 6;
  const int lane = tid & 63;
  const int q    = lane >> 4;
  const int t16  = lane & 15;
  const int erow0 = blockIdx.x * 128;        // global edge base of this block

  if (tid < 128) {
    int e = erow0 + tid;
    int r = eidx[e], c = eidx[ETOT + e];
    float dx = pos[c * 3 + 0] - pos[r * 3 + 0];
    float dy = pos[c * 3 + 1] - pos[r * 3 + 1];
    float dz = pos[c * 3 + 2] - pos[r * 3 + 2];
    float d2 = dx * dx + dy * dy + dz * dz;
    s_erow[tid] = r; s_ecol[tid] = c;
    s_rad[tid]  = 0.01f * d2;                // (ANG_TO_NM)^2 * |dvec|^2
    s_dist[tid] = sqrtf(d2);
  }
  if (tid < 64) s_off[tid] = off[tid];
  s_bias[tid] = bias[tid];
  s_wrad[tid] = wrad[tid];

  // stage B tile [256 n][64 k] (WgT) via async DMA — no dependence on s_*
  #pragma unroll
  for (int ii = 0; ii < 8; ++ii) {
    int i = w * 8 + ii;
    int f = i * 64 + lane;
    int n = f >> 3, s = f & 7;
    int ko = s ^ (n & 7);
    async16(WgT_l + (size_t)n * 64 + ko * 8, smem + 16384 + i * 1024);
  }
  __syncthreads();                           // s_dist/s_off ready

  // Gaussian A tile [128 m][64 k] -> LDS with swizzle, 4 x ds_write_b128/thread
  {
    const float GC = -0.5f / ((5.0f / 63.0f) * (5.0f / 63.0f));
    int m = tid >> 1, half = tid & 1;
    float d = s_dist[m];
    #pragma unroll
    for (int ko2 = 0; ko2 < 4; ++ko2) {
      int ko = half * 4 + ko2;
      bf16x8 v;
      #pragma unroll
      for (int j = 0; j < 8; ++j) {
        float t = d - s_off[ko * 8 + j];
        v[j] = f2bf(__expf(GC * t * t));
      }
      int f = m * 8 + (ko ^ (m & 7));
      *(bf16x8*)(smem + f * 16) = v;
    }
  }
  __syncthreads();                           // drains lgkmcnt (A) + vmcnt (B)

  f32x4 acc[8][4] = {};
  #pragma unroll
  for (int ks = 0; ks < 2; ++ks) {
    bf16x8 av[8]; bf16x8 bv[4];
    const int ko = q + 4 * ks;
    #pragma unroll
    for (int mi = 0; mi < 8; ++mi) {
      int m = 16 * mi + t16;
      int f = m * 8 + (ko ^ (m & 7));
      av[mi] = *(const bf16x8*)(smem + f * 16);
    }
    #pragma unroll
    for (int ni = 0; ni < 4; ++ni) {
      int n = 64 * w + 16 * ni + t16;
      int f = n * 8 + (ko ^ (n & 7));
      bv[ni] = *(const bf16x8*)(smem + 16384 + f * 16);
    }
    #pragma unroll
    for (int mi = 0; mi < 8; ++mi)
      #pragma unroll
      for (int ni = 0; ni < 4; ++ni)
        acc[mi][ni] = __builtin_amdgcn_mfma_f32_16x16x32_bf16(
            av[mi], bv[ni], acc[mi][ni], 0, 0, 0);
  }

  // ---- epilogue via LDS bridge; half-wave per edge row -> coalesced gathers
  float* lds_f = (float*)smem;               // [16][LDSF_STRIDE]
  #pragma unroll
  for (int mi = 0; mi < 8; ++mi) {
    __syncthreads();
    #pragma unroll
    for (int ni = 0; ni < 4; ++ni)
      #pragma unroll
      for (int r = 0; r < 4; ++r)
        lds_f[(4 * q + r) * LDSF_STRIDE + 64 * w + 16 * ni + t16] = acc[mi][ni][r];
    __syncthreads();
    #pragma unroll
    for (int j = 0; j < 2; ++j) {
      int task = tid + 256 * j;
      int rr = task >> 5, cg = task & 31;
      int c0 = cg * 8;
      int rl = 16 * mi + rr;                 // block-local edge row
      int er = s_erow[rl], ec = s_ecol[rl];
      float rad = s_rad[rl];
      f32x4 v0 = *(const f32x4*)(lds_f + rr * LDSF_STRIDE + c0);
      f32x4 v1 = *(const f32x4*)(lds_f + rr * LDSF_STRIDE + c0 + 4);
      bf16x8 pr = *(const bf16x8*)(Prc + (size_t)er * 512 + c0);
      bf16x8 pc = *(const bf16x8*)(Prc + (size_t)ec * 512 + 256 + c0);
      float v[8] = {v0[0], v0[1], v0[2], v0[3], v1[0], v1[1], v1[2], v1[3]};
      bf16x8 o;
      #pragma unroll
      for (int k = 0; k < 8; ++k) {
        float val = v[k] + s_bias[c0 + k] + rad * s_wrad[c0 + k]
                  + bf2f(pr[k]) + bf2f(pc[k]);
        o[k] = f2bf(fmaxf(val, 0.f));
      }
      *(bf16x8*)(Om + ((size_t)erow0 + rl) * 256 + c0) = o;
    }
  }
}

// ---------------------------------------------------------------------------
// Prep kernels: weight repack/transpose to bf16 [n][k] layouts, once per call
// ---------------------------------------------------------------------------
__global__ void wrct_kernel(const float* We1, bf16* WrcT) {
  int idx = blockIdx.x * 256 + threadIdx.x;         // L*512*256
  int k = idx & 255, np = (idx >> 8) & 511, l = idx >> 17;
  float v = (np < 256)
      ? We1[((size_t)l * 577 + k) * 256 + np]
      : We1[((size_t)l * 577 + 256 + k) * 256 + (np - 256)];
  WrcT[idx] = __float2bfloat16(v);
}
__global__ void wgt_kernel(const float* We1, bf16* WgT) {
  int idx = blockIdx.x * 256 + threadIdx.x;         // L*256*64
  int k = idx & 63, n = (idx >> 6) & 255, l = idx >> 14;
  WgT[idx] = __float2bfloat16(We1[((size_t)l * 577 + 513 + k) * 256 + n]);
}
__global__ void wrad_kernel(const float* We1, float* wrad) {
  int idx = blockIdx.x * 256 + threadIdx.x;         // L*256
  int n = idx & 255, l = idx >> 8;
  wrad[idx] = We1[((size_t)l * 577 + 512) * 256 + n];
}
__global__ void trans_kernel(const float* src, bf16* dst, int R, int C) {
  int idx = blockIdx.x * 256 + threadIdx.x;         // L*C*R, dst [l][n][k]
  int k = idx % R, rest = idx / R;
  int n = rest % C, l = rest / C;
  dst[idx] = __float2bfloat16(src[((size_t)l * R + k) * C + n]);
}

__global__ void h0_kernel(const int* types, const float* emb, float* h, bf16* hbf) {
  int i = blockIdx.x, c = threadIdx.x;
  float v = emb[(size_t)(types[i] - 1) * 256 + c];
  h[(size_t)i * 256 + c] = v;
  hbf[(size_t)i * 256 + c] = __float2bfloat16(v);
}

// segment-sum: 20 row-sorted edges per node, vectorized 16B (8 ch / thread)
__global__ void __launch_bounds__(256)
agg_kernel(const bf16* m, bf16* aggbf) {
  int idx = blockIdx.x * 256 + threadIdx.x;   // NATOMS*32 threads
  int v = idx >> 5, c8 = (idx & 31) * 8;
  const bf16* p = m + (size_t)v * 20 * 256 + c8;
  float s[8] = {0.f, 0.f, 0.f, 0.f, 0.f, 0.f, 0.f, 0.f};
  #pragma unroll
  for (int j = 0; j < 20; ++j) {
    bf16x8 vv = *(const bf16x8*)(p + (size_t)j * 256);
    #pragma unroll
    for (int k = 0; k < 8; ++k) s[k] += bf2f(vv[k]);
  }
  bf16x8 o;
  #pragma unroll
  for (int k = 0; k < 8; ++k) o[k] = f2bf(s[k]);
  *(bf16x8*)(aggbf + (size_t)v * 256 + c8) = o;
}

// global mean pool over 32 atoms per building block
__global__ void pool_kernel(const float* h, float* out) {
  int b = blockIdx.x, c = threadIdx.x;
  float s = 0.f;
  #pragma unroll
  for (int j = 0; j < 32; ++j) s += h[((size_t)b * 32 + j) * 256 + c];
  out[(size_t)b * 256 + c] = s * (1.0f / 32.0f);
}

// ---------------------------------------------------------------------------
extern "C" void kernel_launch(void* const* d_in, const int* in_sizes, int n_in,
                              void* d_out, int out_size, void* d_ws, size_t ws_size,
                              hipStream_t stream) {
  const float* pos   = (const float*)d_in[0];
  const int*   atype = (const int*)  d_in[1];
  const int*   eidx  = (const int*)  d_in[2];
  const float* emb   = (const float*)d_in[4];
  const float* off   = (const float*)d_in[5];
  const float* We1   = (const float*)d_in[6];
  const float* be1   = (const float*)d_in[7];
  const float* We2   = (const float*)d_in[8];
  const float* be2   = (const float*)d_in[9];
  const float* Wn1   = (const float*)d_in[10];
  const float* bn1   = (const float*)d_in[11];
  const float* Wn2   = (const float*)d_in[12];
  const float* bn2   = (const float*)d_in[13];
  float* out = (float*)d_out;

  // ---- workspace carve (256B aligned, ~221 MB total; ws_size = 256 MiB) ----
  size_t o = 0;
  auto carve = [&](size_t bytes) {
    void* p = (char*)d_ws + o;
    o += (bytes + 255) & ~(size_t)255;
    return p;
  };
  float* h     = (float*)carve((size_t)NATOMS * 256 * 4);   // 16 MB
  bf16*  hbf   = (bf16*) carve((size_t)NATOMS * 256 * 2);   //  8 MB
  bf16*  Prc   = (bf16*) carve((size_t)NATOMS * 512 * 2);   // 16 MB
  bf16*  m     = (bf16*) carve((size_t)ETOT * 256 * 2);     // 160 MB (MLP1->MLP2 in-place)
  bf16*  aggbf = (bf16*) carve((size_t)NATOMS * 256 * 2);   //  8 MB (agg, then nMLP1 out)
  bf16*  WrcT  = (bf16*) carve((size_t)NLAYER * 512 * 256 * 2);
  bf16*  WgT   = (bf16*) carve((size_t)NLAYER * 256 * 64 * 2);
  bf16*  We2T  = (bf16*) carve((size_t)NLAYER * 256 * 256 * 2);
  bf16*  Wn1T  = (bf16*) carve((size_t)NLAYER * 256 * 512 * 2);
  bf16*  Wn2T  = (bf16*) carve((size_t)NLAYER * 256 * 256 * 2);
  float* wradp = (float*)carve((size_t)NLAYER * 256 * 4);

  // ---- prep: weights -> bf16 transposed, h0 gather ----
  wrct_kernel<<<2048, 256, 0, stream>>>(We1, WrcT);
  wgt_kernel <<< 256, 256, 0, stream>>>(We1, WgT);
  wrad_kernel<<<   4, 256, 0, stream>>>(We1, wradp);
  trans_kernel<<<1024, 256, 0, stream>>>(We2, We2T, 256, 256);
  trans_kernel<<<2048, 256, 0, stream>>>(Wn1, Wn1T, 512, 256);
  trans_kernel<<<1024, 256, 0, stream>>>(Wn2, Wn2T, 256, 256);
  h0_kernel  <<<NATOMS, 256, 0, stream>>>(atype, emb, h, hbf);

  // ---- layers ----
  for (int l = 0; l < NLAYER; ++l) {
    // Prc[N,512] = h @ [We1_r | We1_c]   (64-row tiles -> 512 blocks)
    gemm_k<256, 0, 64><<<dim3(256, 2), 256, 0, stream>>>(
        hbf, nullptr, WrcT + (size_t)l * 512 * 256, Prc, 512, nullptr,
        nullptr, nullptr);
    // m[E,256] = relu(gauss(dist)@W_g + P_r[row] + P_c[col] + radial*w_rad + be1)
    gemm_edge1<<<ETOT / 128, 256, 0, stream>>>(
        WgT + (size_t)l * 256 * 64, off, pos, eidx, Prc,
        be1 + l * 256, wradp + l * 256, m);
    // m = relu(m @ We2 + be2), in-place
    gemm_k<256, 2, 128><<<dim3(ETOT / 128, 1), 256, 0, stream>>>(
        m, nullptr, We2T + (size_t)l * 256 * 256, m, 256, be2 + l * 256,
        nullptr, nullptr);
    // agg[N,256] = segment_sum (20 edges/node), 16B vectorized
    agg_kernel<<<NATOMS * 32 / 256, 256, 0, stream>>>(m, aggbf);
    // t[N,256] = relu([h|agg] @ Wn1 + bn1), in-place into aggbf
    gemm_k<512, 2, 64><<<dim3(256, 1), 256, 0, stream>>>(
        hbf, aggbf, Wn1T + (size_t)l * 256 * 512, aggbf, 256, bn1 + l * 256,
        nullptr, nullptr);
    // h = 2h + (t @ Wn2 + bn2)
    gemm_k<256, 4, 64><<<dim3(256, 1), 256, 0, stream>>>(
        aggbf, nullptr, Wn2T + (size_t)l * 256 * 256, nullptr, 0, bn2 + l * 256,
        h, hbf);
  }

  pool_kernel<<<512, 256, 0, stream>>>(h, out);
}

// Round 5
// 710.359 us; speedup vs baseline: 2.0383x; 1.3906x over previous
//
#include <hip/hip_runtime.h>
#include <hip/hip_bf16.h>
#include <stdint.h>

// Problem constants (fixed by reference setup)
#define NATOMS 16384          // B*NPB = 512*32
#define ETOT   327680         // NATOMS*K (K=20 neighbors)
#define NLAYER 4

typedef __hip_bfloat16 bf16;
using bf16x8 = __attribute__((ext_vector_type(8))) short;   // MFMA A/B frag (4 VGPRs)
using f32x4  = __attribute__((ext_vector_type(4))) float;   // MFMA C/D frag

#define LDSF_STRIDE 260   // f32 words per barrier-bridge row (gemm_k)
#define WBR_STRIDE  66    // f32 words per wave-private bridge row (edge1)

__device__ __forceinline__ float bf2f(short s) {
  union { float f; unsigned u; } x; x.u = ((unsigned)(unsigned short)s) << 16; return x.f;
}
__device__ __forceinline__ short f2bf(float f) {
  bf16 b = __float2bfloat16(f);
  return *(short*)&b;
}

// ---------------------------------------------------------------------------
// async global->LDS 16B (direct-to-LDS DMA; dest = wave-uniform base + lane*16)
// ---------------------------------------------------------------------------
__device__ __forceinline__ void async16(const void* g, void* l) {
  __builtin_amdgcn_global_load_lds(
      (const __attribute__((address_space(1))) unsigned int*)g,
      (__attribute__((address_space(3))) unsigned int*)l, 16, 0, 0);
}

// ---------------------------------------------------------------------------
// Tiled bf16 MFMA GEMM: C[MT x 256] per block, 4 waves (64 cols each),
// K in chunks of 64.  MT in {64,128}.
//  A: [M][KTOT] bf16 row-major (KTOT=512: rows are [A | A2], 256 each)
//  B: [Ncols][KTOT] bf16  (W^T, n-major) -> contiguous k-octets per n
// LDS swizzle: octet (r, ko) lives at 16B-slot f = r*8 + (ko ^ (r&7)); the
// global source address is permuted so the LDS image stays a linear
// global_load_lds target.
// Epilogues (through barrier'd LDS f32 bridge for coalesced bf16x8 stores):
//  0: store bf16 at ldOut (h @ [We1_r|We1_c] -> Prc)
//  2: += bias, relu, store bf16 (node MLP1 in-place)
//  4: += bias; h = 2*h + val; store h f32 + bf16 (node MLP2 + residuals)
// ---------------------------------------------------------------------------
template<int KTOT, int EPI, int MT>
__global__ void __launch_bounds__(256, 2)
gemm_k(const bf16* A, const bf16* A2, const bf16* B,
       bf16* Obf, int ldOut, const float* bias,
       float* Hf, bf16* Hbf)
{
  __shared__ __align__(16) char smem[49152];   // A tile @0 (<=16KB), B tile 32KB @16384
  __shared__ float s_bias[256];

  const int tid  = threadIdx.x;
  const int w    = tid >> 6;        // wave 0..3 (owns 64-col slice)
  const int lane = tid & 63;
  const int q    = lane >> 4;       // quad
  const int t16  = lane & 15;
  const size_t row0 = (size_t)blockIdx.x * MT;
  const int ncol0 = blockIdx.y * 256;
  constexpr int MI = MT / 16;       // row-tiles per wave
  constexpr int AI = MT / 32;       // A-stage issues per wave (MT/8 total /4)

  if constexpr (EPI == 2 || EPI == 4) s_bias[tid] = bias[tid];

  f32x4 acc[MI][4] = {};

  constexpr int NCHUNK = KTOT / 64;
  for (int kc = 0; kc < NCHUNK; ++kc) {
    const int k0 = kc * 64;
    const bf16* Asrc; int k0e; int ldA;
    if constexpr (KTOT == 512) {            // node MLP1: concat [h | agg]
      if (k0 < 256) { Asrc = A;  k0e = k0;       }
      else          { Asrc = A2; k0e = k0 - 256; }
      ldA = 256;
    } else {
      Asrc = A; k0e = k0; ldA = KTOT;
    }

    __syncthreads();                         // previous chunk's LDS reads done
    // stage A tile [MT][64]
    #pragma unroll
    for (int ii = 0; ii < AI; ++ii) {
      int i = w * AI + ii;
      int f = i * 64 + lane;                 // 16B slot index
      int m = f >> 3, s = f & 7;
      int ko = s ^ (m & 7);                  // which global k-octet goes here
      const bf16* g = Asrc + (row0 + (size_t)m) * ldA + (size_t)(k0e + ko * 8);
      async16(g, smem + i * 1024);
    }
    // stage B tile [256 n][64 k] = 32 issues (8 per wave)
    #pragma unroll
    for (int ii = 0; ii < 8; ++ii) {
      int i = w * 8 + ii;
      int f = i * 64 + lane;
      int n = f >> 3, s = f & 7;
      int ko = s ^ (n & 7);
      const bf16* g = B + (size_t)(ncol0 + n) * KTOT + (size_t)(k0 + ko * 8);
      async16(g, smem + 16384 + i * 1024);
    }
    __syncthreads();                         // drains vmcnt before barrier

    #pragma unroll
    for (int ks = 0; ks < 2; ++ks) {
      bf16x8 av[MI]; bf16x8 bv[4];
      const int ko = q + 4 * ks;             // operand: k = ko*8 + j
      #pragma unroll
      for (int mi = 0; mi < MI; ++mi) {      // A: m = lane&15, k = quad*8+j
        int m = 16 * mi + t16;
        int f = m * 8 + (ko ^ (m & 7));
        av[mi] = *(const bf16x8*)(smem + f * 16);
      }
      #pragma unroll
      for (int ni = 0; ni < 4; ++ni) {       // B: n = lane&15, k = quad*8+j
        int n = 64 * w + 16 * ni + t16;
        int f = n * 8 + (ko ^ (n & 7));
        bv[ni] = *(const bf16x8*)(smem + 16384 + f * 16);
      }
      #pragma unroll
      for (int mi = 0; mi < MI; ++mi)
        #pragma unroll
        for (int ni = 0; ni < 4; ++ni)
          acc[mi][ni] = __builtin_amdgcn_mfma_f32_16x16x32_bf16(
              av[mi], bv[ni], acc[mi][ni], 0, 0, 0);
    }
  }

  // ---- epilogue via LDS transpose bridge ----
  // MFMA C/D layout: col = lane&15, row = quad*4 + reg  [m89-verified]
  float* lds_f = (float*)smem;               // [16][LDSF_STRIDE] chunk
  #pragma unroll
  for (int mi = 0; mi < MI; ++mi) {
    __syncthreads();                         // prev chunk consumed / K-loop reads done
    #pragma unroll
    for (int ni = 0; ni < 4; ++ni)
      #pragma unroll
      for (int r = 0; r < 4; ++r)
        lds_f[(4 * q + r) * LDSF_STRIDE + 64 * w + 16 * ni + t16] = acc[mi][ni][r];
    __syncthreads();
    #pragma unroll
    for (int j = 0; j < 2; ++j) {
      int task = tid + 256 * j;              // 512 tasks: 16 rows x 32 col-octets
      int rr = task >> 5, cg = task & 31;
      int c0 = cg * 8;
      size_t rg = row0 + 16 * mi + rr;
      f32x4 v0 = *(const f32x4*)(lds_f + rr * LDSF_STRIDE + c0);
      f32x4 v1 = *(const f32x4*)(lds_f + rr * LDSF_STRIDE + c0 + 4);
      float v[8] = {v0[0], v0[1], v0[2], v0[3], v1[0], v1[1], v1[2], v1[3]};
      if constexpr (EPI == 0) {
        bf16x8 o;
        #pragma unroll
        for (int k = 0; k < 8; ++k) o[k] = f2bf(v[k]);
        *(bf16x8*)(Obf + rg * ldOut + (ncol0 + c0)) = o;
      } else if constexpr (EPI == 2) {
        bf16x8 o;
        #pragma unroll
        for (int k = 0; k < 8; ++k) o[k] = f2bf(fmaxf(v[k] + s_bias[c0 + k], 0.f));
        *(bf16x8*)(Obf + rg * 256 + c0) = o;
      } else {  // EPI == 4: h_new = 2*h + (acc + bias)
        f32x4 h0 = *(const f32x4*)(Hf + rg * 256 + c0);
        f32x4 h1 = *(const f32x4*)(Hf + rg * 256 + c0 + 4);
        float hh[8] = {h0[0], h0[1], h0[2], h0[3], h1[0], h1[1], h1[2], h1[3]};
        bf16x8 o; f32x4 n0, n1;
        #pragma unroll
        for (int k = 0; k < 8; ++k) {
          float hn = 2.f * hh[k] + v[k] + s_bias[c0 + k];
          o[k] = f2bf(hn);
          if (k < 4) n0[k] = hn; else n1[k - 4] = hn;
        }
        *(f32x4*)(Hf + rg * 256 + c0)     = n0;
        *(f32x4*)(Hf + rg * 256 + c0 + 4) = n1;
        *(bf16x8*)(Hbf + rg * 256 + c0) = o;
      }
    }
  }
}

// ---------------------------------------------------------------------------
// Edge MLP1 (fused): per block 128 edges. Computes dist/radial from pos+eidx,
// builds the Gaussian A-tile [128][64] directly in LDS, stages WgT via
// async16, one K=64 MFMA pass. Epilogue uses a WAVE-PRIVATE LDS bridge
// (no barriers -> mi iterations software-pipeline; Prc gathers overlap).
// ---------------------------------------------------------------------------
__global__ void __launch_bounds__(256, 2)
gemm_edge1(const bf16* WgT_l, const float* off, const float* pos,
           const int* eidx, const bf16* Prc,
           const float* bias, const float* wrad, bf16* Om)
{
  __shared__ __align__(16) char smem[49152];
  __shared__ int   s_erow[128];
  __shared__ int   s_ecol[128];
  __shared__ float s_rad[128];
  __shared__ float s_dist[128];
  __shared__ float s_bias[256];
  __shared__ float s_wrad[256];
  __shared__ float s_off[64];

  const int tid  = threadIdx.x;
  const int w    = tid >> 6;
  const int lane = tid & 63;
  const int q    = lane >> 4;
  const int t16  = lane & 15;
  const int erow0 = blockIdx.x * 128;        // global edge base of this block

  if (tid < 128) {
    int e = erow0 + tid;
    int r = eidx[e], c = eidx[ETOT + e];
    float dx = pos[c * 3 + 0] - pos[r * 3 + 0];
    float dy = pos[c * 3 + 1] - pos[r * 3 + 1];
    float dz = pos[c * 3 + 2] - pos[r * 3 + 2];
    float d2 = dx * dx + dy * dy + dz * dz;
    s_erow[tid] = r; s_ecol[tid] = c;
    s_rad[tid]  = 0.01f * d2;                // (ANG_TO_NM)^2 * |dvec|^2
    s_dist[tid] = sqrtf(d2);
  }
  if (tid < 64) s_off[tid] = off[tid];
  s_bias[tid] = bias[tid];
  s_wrad[tid] = wrad[tid];

  // stage B tile [256 n][64 k] (WgT) via async DMA — no dependence on s_*
  #pragma unroll
  for (int ii = 0; ii < 8; ++ii) {
    int i = w * 8 + ii;
    int f = i * 64 + lane;
    int n = f >> 3, s = f & 7;
    int ko = s ^ (n & 7);
    async16(WgT_l + (size_t)n * 64 + ko * 8, smem + 16384 + i * 1024);
  }
  __syncthreads();                           // s_dist/s_off ready

  // Gaussian A tile [128 m][64 k] -> LDS with swizzle
  {
    const float GC = -0.5f / ((5.0f / 63.0f) * (5.0f / 63.0f));
    int m = tid >> 1, half = tid & 1;
    float d = s_dist[m];
    #pragma unroll
    for (int ko2 = 0; ko2 < 4; ++ko2) {
      int ko = half * 4 + ko2;
      bf16x8 v;
      #pragma unroll
      for (int j = 0; j < 8; ++j) {
        float t = d - s_off[ko * 8 + j];
        v[j] = f2bf(__expf(GC * t * t));
      }
      int f = m * 8 + (ko ^ (m & 7));
      *(bf16x8*)(smem + f * 16) = v;
    }
  }
  __syncthreads();                           // drains lgkmcnt (A) + vmcnt (B)

  f32x4 acc[8][4] = {};
  #pragma unroll
  for (int ks = 0; ks < 2; ++ks) {
    bf16x8 av[8]; bf16x8 bv[4];
    const int ko = q + 4 * ks;
    #pragma unroll
    for (int mi = 0; mi < 8; ++mi) {
      int m = 16 * mi + t16;
      int f = m * 8 + (ko ^ (m & 7));
      av[mi] = *(const bf16x8*)(smem + f * 16);
    }
    #pragma unroll
    for (int ni = 0; ni < 4; ++ni) {
      int n = 64 * w + 16 * ni + t16;
      int f = n * 8 + (ko ^ (n & 7));
      bv[ni] = *(const bf16x8*)(smem + 16384 + f * 16);
    }
    #pragma unroll
    for (int mi = 0; mi < 8; ++mi)
      #pragma unroll
      for (int ni = 0; ni < 4; ++ni)
        acc[mi][ni] = __builtin_amdgcn_mfma_f32_16x16x32_bf16(
            av[mi], bv[ni], acc[mi][ni], 0, 0, 0);
  }

  // ---- wave-private bridge epilogue: ONE barrier, then no syncs ----
  __syncthreads();                           // all waves done reading B region
  float* br = (float*)(smem + 16384 + w * 4608);   // [16][WBR_STRIDE] f32, per wave
  const int rs = lane >> 3, oct = lane & 7;
  const int c0e = 64 * w + oct * 8;          // fixed cols per lane
  float bias8[8], wrad8[8];
  #pragma unroll
  for (int k = 0; k < 8; ++k) { bias8[k] = s_bias[c0e + k]; wrad8[k] = s_wrad[c0e + k]; }

  #pragma unroll
  for (int mi = 0; mi < 8; ++mi) {
    // transpose this wave's 16x64 chunk (rows 16mi.., cols 64w..)
    #pragma unroll
    for (int ni = 0; ni < 4; ++ni)
      #pragma unroll
      for (int r = 0; r < 4; ++r)
        br[(4 * q + r) * WBR_STRIDE + 16 * ni + t16] = acc[mi][ni][r];
    #pragma unroll
    for (int pass = 0; pass < 2; ++pass) {
      int rr = pass * 8 + rs;
      int rl = 16 * mi + rr;
      int er = s_erow[rl], ec = s_ecol[rl];
      float rad = s_rad[rl];
      bf16x8 pr = *(const bf16x8*)(Prc + (size_t)er * 512 + c0e);
      bf16x8 pc = *(const bf16x8*)(Prc + (size_t)ec * 512 + 256 + c0e);
      float v[8];
      #pragma unroll
      for (int jj = 0; jj < 4; ++jj) {
        float2 t = *(const float2*)(br + rr * WBR_STRIDE + oct * 8 + 2 * jj);
        v[2 * jj] = t.x; v[2 * jj + 1] = t.y;
      }
      bf16x8 o;
      #pragma unroll
      for (int k = 0; k < 8; ++k) {
        float val = v[k] + bias8[k] + rad * wrad8[k] + bf2f(pr[k]) + bf2f(pc[k]);
        o[k] = f2bf(fmaxf(val, 0.f));
      }
      *(bf16x8*)(Om + ((size_t)(erow0 + rl)) * 256 + c0e) = o;
    }
  }
}

// ---------------------------------------------------------------------------
// Fused edge MLP2 + segment-sum: block = 80 edges = exactly 4 nodes.
// m[e] = relu(m1[e] @ We2 + be2) is never materialized: each f32x4 acc
// register group (4 consecutive rows, since 4|20) lies in ONE node
// (group g = 4*mi+q, node = g/5), so the 20-row segment sum is an in-lane
// sum over r/mi plus a 2-step shfl_xor butterfly over the quad bits.
// Writes only Agg[node][256] bf16.
// ---------------------------------------------------------------------------
__global__ void __launch_bounds__(256, 2)
gemm_edge2agg(const bf16* M1, const bf16* We2T_l, const float* bias, bf16* Agg)
{
  __shared__ __align__(16) char smem[43008];  // A [80][64] 10KB @0, B 32KB @10240
  __shared__ float s_bias[256];

  const int tid  = threadIdx.x;
  const int w    = tid >> 6;
  const int lane = tid & 63;
  const int q    = lane >> 4;
  const int t16  = lane & 15;
  const size_t erow0 = (size_t)blockIdx.x * 80;

  s_bias[tid] = bias[tid];

  f32x4 acc[5][4] = {};
  for (int kc = 0; kc < 4; ++kc) {          // K = 256
    const int k0 = kc * 64;
    __syncthreads();
    for (int i = w; i < 10; i += 4) {       // A tile [80][64]
      int f = i * 64 + lane;
      int m = f >> 3, s = f & 7;
      int ko = s ^ (m & 7);
      async16(M1 + (erow0 + (size_t)m) * 256 + (size_t)(k0 + ko * 8), smem + i * 1024);
    }
    #pragma unroll
    for (int ii = 0; ii < 8; ++ii) {        // B tile [256][64]
      int i = w * 8 + ii;
      int f = i * 64 + lane;
      int n = f >> 3, s = f & 7;
      int ko = s ^ (n & 7);
      async16(We2T_l + (size_t)n * 256 + (size_t)(k0 + ko * 8), smem + 10240 + i * 1024);
    }
    __syncthreads();

    #pragma unroll
    for (int ks = 0; ks < 2; ++ks) {
      bf16x8 av[5]; bf16x8 bv[4];
      const int ko = q + 4 * ks;
      #pragma unroll
      for (int mi = 0; mi < 5; ++mi) {
        int m = 16 * mi + t16;
        int f = m * 8 + (ko ^ (m & 7));
        av[mi] = *(const bf16x8*)(smem + f * 16);
      }
      #pragma unroll
      for (int ni = 0; ni < 4; ++ni) {
        int n = 64 * w + 16 * ni + t16;
        int f = n * 8 + (ko ^ (n & 7));
        bv[ni] = *(const bf16x8*)(smem + 10240 + f * 16);
      }
      #pragma unroll
      for (int mi = 0; mi < 5; ++mi)
        #pragma unroll
        for (int ni = 0; ni < 4; ++ni)
          acc[mi][ni] = __builtin_amdgcn_mfma_f32_16x16x32_bf16(
              av[mi], bv[ni], acc[mi][ni], 0, 0, 0);
    }
  }

  // ---- register-space relu + segment-sum (no LDS, no barriers) ----
  #pragma unroll
  for (int ni = 0; ni < 4; ++ni) {
    float b = s_bias[64 * w + 16 * ni + t16];
    float pp[5];
    #pragma unroll
    for (int mi = 0; mi < 5; ++mi) {
      float s = 0.f;
      #pragma unroll
      for (int r = 0; r < 4; ++r) s += fmaxf(acc[mi][ni][r] + b, 0.f);
      pp[mi] = s;
    }
    #pragma unroll
    for (int nn = 0; nn < 4; ++nn) {        // node nn: groups g in [5nn, 5nn+4]
      float s = 0.f;
      #pragma unroll
      for (int mi = 0; mi < 5; ++mi) {
        int g = 4 * mi + q;
        if (g >= 5 * nn && g <= 5 * nn + 4) s += pp[mi];
      }
      s += __shfl_xor(s, 16, 64);           // reduce over quad bit 0
      s += __shfl_xor(s, 32, 64);           // reduce over quad bit 1
      if (q == nn)
        Agg[((size_t)blockIdx.x * 4 + nn) * 256 + 64 * w + 16 * ni + t16] =
            __float2bfloat16(s);
    }
  }
}

// ---------------------------------------------------------------------------
// Prep kernels: weight repack/transpose to bf16 [n][k] layouts, once per call
// ---------------------------------------------------------------------------
__global__ void wrct_kernel(const float* We1, bf16* WrcT) {
  int idx = blockIdx.x * 256 + threadIdx.x;         // L*512*256
  int k = idx & 255, np = (idx >> 8) & 511, l = idx >> 17;
  float v = (np < 256)
      ? We1[((size_t)l * 577 + k) * 256 + np]
      : We1[((size_t)l * 577 + 256 + k) * 256 + (np - 256)];
  WrcT[idx] = __float2bfloat16(v);
}
__global__ void wgt_kernel(const float* We1, bf16* WgT) {
  int idx = blockIdx.x * 256 + threadIdx.x;         // L*256*64
  int k = idx & 63, n = (idx >> 6) & 255, l = idx >> 14;
  WgT[idx] = __float2bfloat16(We1[((size_t)l * 577 + 513 + k) * 256 + n]);
}
__global__ void wrad_kernel(const float* We1, float* wrad) {
  int idx = blockIdx.x * 256 + threadIdx.x;         // L*256
  int n = idx & 255, l = idx >> 8;
  wrad[idx] = We1[((size_t)l * 577 + 512) * 256 + n];
}
__global__ void trans_kernel(const float* src, bf16* dst, int R, int C) {
  int idx = blockIdx.x * 256 + threadIdx.x;         // L*C*R, dst [l][n][k]
  int k = idx % R, rest = idx / R;
  int n = rest % C, l = rest / C;
  dst[idx] = __float2bfloat16(src[((size_t)l * R + k) * C + n]);
}

__global__ void h0_kernel(const int* types, const float* emb, float* h, bf16* hbf) {
  int i = blockIdx.x, c = threadIdx.x;
  float v = emb[(size_t)(types[i] - 1) * 256 + c];
  h[(size_t)i * 256 + c] = v;
  hbf[(size_t)i * 256 + c] = __float2bfloat16(v);
}

// global mean pool over 32 atoms per building block
__global__ void pool_kernel(const float* h, float* out) {
  int b = blockIdx.x, c = threadIdx.x;
  float s = 0.f;
  #pragma unroll
  for (int j = 0; j < 32; ++j) s += h[((size_t)b * 32 + j) * 256 + c];
  out[(size_t)b * 256 + c] = s * (1.0f / 32.0f);
}

// ---------------------------------------------------------------------------
extern "C" void kernel_launch(void* const* d_in, const int* in_sizes, int n_in,
                              void* d_out, int out_size, void* d_ws, size_t ws_size,
                              hipStream_t stream) {
  const float* pos   = (const float*)d_in[0];
  const int*   atype = (const int*)  d_in[1];
  const int*   eidx  = (const int*)  d_in[2];
  const float* emb   = (const float*)d_in[4];
  const float* off   = (const float*)d_in[5];
  const float* We1   = (const float*)d_in[6];
  const float* be1   = (const float*)d_in[7];
  const float* We2   = (const float*)d_in[8];
  const float* be2   = (const float*)d_in[9];
  const float* Wn1   = (const float*)d_in[10];
  const float* bn1   = (const float*)d_in[11];
  const float* Wn2   = (const float*)d_in[12];
  const float* bn2   = (const float*)d_in[13];
  float* out = (float*)d_out;

  // ---- workspace carve (256B aligned, ~221 MB total; ws_size = 256 MiB) ----
  size_t o = 0;
  auto carve = [&](size_t bytes) {
    void* p = (char*)d_ws + o;
    o += (bytes + 255) & ~(size_t)255;
    return p;
  };
  float* h     = (float*)carve((size_t)NATOMS * 256 * 4);   // 16 MB
  bf16*  hbf   = (bf16*) carve((size_t)NATOMS * 256 * 2);   //  8 MB
  bf16*  Prc   = (bf16*) carve((size_t)NATOMS * 512 * 2);   // 16 MB
  bf16*  m1    = (bf16*) carve((size_t)ETOT * 256 * 2);     // 160 MB
  bf16*  aggbf = (bf16*) carve((size_t)NATOMS * 256 * 2);   //  8 MB (agg, then nMLP1 out)
  bf16*  WrcT  = (bf16*) carve((size_t)NLAYER * 512 * 256 * 2);
  bf16*  WgT   = (bf16*) carve((size_t)NLAYER * 256 * 64 * 2);
  bf16*  We2T  = (bf16*) carve((size_t)NLAYER * 256 * 256 * 2);
  bf16*  Wn1T  = (bf16*) carve((size_t)NLAYER * 256 * 512 * 2);
  bf16*  Wn2T  = (bf16*) carve((size_t)NLAYER * 256 * 256 * 2);
  float* wradp = (float*)carve((size_t)NLAYER * 256 * 4);

  // ---- prep: weights -> bf16 transposed, h0 gather ----
  wrct_kernel<<<2048, 256, 0, stream>>>(We1, WrcT);
  wgt_kernel <<< 256, 256, 0, stream>>>(We1, WgT);
  wrad_kernel<<<   4, 256, 0, stream>>>(We1, wradp);
  trans_kernel<<<1024, 256, 0, stream>>>(We2, We2T, 256, 256);
  trans_kernel<<<2048, 256, 0, stream>>>(Wn1, Wn1T, 512, 256);
  trans_kernel<<<1024, 256, 0, stream>>>(Wn2, Wn2T, 256, 256);
  h0_kernel  <<<NATOMS, 256, 0, stream>>>(atype, emb, h, hbf);

  // ---- layers ----
  for (int l = 0; l < NLAYER; ++l) {
    // Prc[N,512] = h @ [We1_r | We1_c]
    gemm_k<256, 0, 64><<<dim3(256, 2), 256, 0, stream>>>(
        hbf, nullptr, WrcT + (size_t)l * 512 * 256, Prc, 512, nullptr,
        nullptr, nullptr);
    // m1[E,256] = relu(gauss(dist)@W_g + P_r[row] + P_c[col] + radial*w_rad + be1)
    gemm_edge1<<<ETOT / 128, 256, 0, stream>>>(
        WgT + (size_t)l * 256 * 64, off, pos, eidx, Prc,
        be1 + l * 256, wradp + l * 256, m1);
    // agg[N,256] = segment_sum(relu(m1 @ We2 + be2)) — fused, m never stored
    gemm_edge2agg<<<ETOT / 80, 256, 0, stream>>>(
        m1, We2T + (size_t)l * 256 * 256, be2 + l * 256, aggbf);
    // t[N,256] = relu([h|agg] @ Wn1 + bn1), in-place into aggbf
    gemm_k<512, 2, 64><<<dim3(256, 1), 256, 0, stream>>>(
        hbf, aggbf, Wn1T + (size_t)l * 256 * 512, aggbf, 256, bn1 + l * 256,
        nullptr, nullptr);
    // h = 2h + (t @ Wn2 + bn2)
    gemm_k<256, 4, 64><<<dim3(256, 1), 256, 0, stream>>>(
        aggbf, nullptr, Wn2T + (size_t)l * 256 * 256, nullptr, 0, bn2 + l * 256,
        h, hbf);
  }

  pool_kernel<<<512, 256, 0, stream>>>(h, out);
}

// Round 6
// 645.387 us; speedup vs baseline: 2.2436x; 1.1007x over previous
//
#include <hip/hip_runtime.h>
#include <hip/hip_bf16.h>
#include <stdint.h>

// Problem constants (fixed by reference setup)
#define NATOMS 16384          // B*NPB = 512*32
#define ETOT   327680         // NATOMS*K (K=20 neighbors)
#define NLAYER 4

typedef __hip_bfloat16 bf16;
using bf16x8 = __attribute__((ext_vector_type(8))) short;   // MFMA A/B frag (4 VGPRs)
using f32x4  = __attribute__((ext_vector_type(4))) float;   // MFMA C/D frag

#define LDSF_STRIDE 260   // f32 words per barrier-bridge row (gemm_k)
#define WBR_STRIDE  66    // f32 words per wave-private bridge row

__device__ __forceinline__ float bf2f(short s) {
  union { float f; unsigned u; } x; x.u = ((unsigned)(unsigned short)s) << 16; return x.f;
}
__device__ __forceinline__ short f2bf(float f) {
  bf16 b = __float2bfloat16(f);
  return *(short*)&b;
}

// ---------------------------------------------------------------------------
// async global->LDS 16B (direct-to-LDS DMA; dest = wave-uniform base + lane*16)
// ---------------------------------------------------------------------------
__device__ __forceinline__ void async16(const void* g, void* l) {
  __builtin_amdgcn_global_load_lds(
      (const __attribute__((address_space(1))) unsigned int*)g,
      (__attribute__((address_space(3))) unsigned int*)l, 16, 0, 0);
}

// ---------------------------------------------------------------------------
// Tiled bf16 MFMA GEMM: C[MT x 256] per block, 4 waves (64 cols each),
// K in chunks of 64.  MT in {64,128}.
//  A: [M][KTOT] bf16 row-major (KTOT=512: rows are [A | A2], 256 each)
//  B: [Ncols][KTOT] bf16  (W^T, n-major) -> contiguous k-octets per n
// LDS swizzle: octet (r, ko) lives at 16B-slot f = r*8 + (ko ^ (r&7)); the
// global source address is permuted so the LDS image stays a linear
// global_load_lds target.
// Epilogues (through barrier'd LDS f32 bridge for coalesced bf16x8 stores):
//  0: store bf16 at ldOut (h @ [We1_r|We1_c] -> Prc)
//  2: += bias, relu, store bf16 (node MLP1 in-place)
//  4: += bias; h = 2*h + val; store h f32 + bf16 (node MLP2 + residuals)
// ---------------------------------------------------------------------------
template<int KTOT, int EPI, int MT>
__global__ void __launch_bounds__(256, 2)
gemm_k(const bf16* A, const bf16* A2, const bf16* B,
       bf16* Obf, int ldOut, const float* bias,
       float* Hf, bf16* Hbf)
{
  __shared__ __align__(16) char smem[49152];   // A tile @0 (<=16KB), B tile 32KB @16384
  __shared__ float s_bias[256];

  const int tid  = threadIdx.x;
  const int w    = tid >> 6;        // wave 0..3 (owns 64-col slice)
  const int lane = tid & 63;
  const int q    = lane >> 4;       // quad
  const int t16  = lane & 15;
  const size_t row0 = (size_t)blockIdx.x * MT;
  const int ncol0 = blockIdx.y * 256;
  constexpr int MI = MT / 16;       // row-tiles per wave
  constexpr int AI = MT / 32;       // A-stage issues per wave (MT/8 total /4)

  if constexpr (EPI == 2 || EPI == 4) s_bias[tid] = bias[tid];

  f32x4 acc[MI][4] = {};

  constexpr int NCHUNK = KTOT / 64;
  for (int kc = 0; kc < NCHUNK; ++kc) {
    const int k0 = kc * 64;
    const bf16* Asrc; int k0e; int ldA;
    if constexpr (KTOT == 512) {            // node MLP1: concat [h | agg]
      if (k0 < 256) { Asrc = A;  k0e = k0;       }
      else          { Asrc = A2; k0e = k0 - 256; }
      ldA = 256;
    } else {
      Asrc = A; k0e = k0; ldA = KTOT;
    }

    __syncthreads();                         // previous chunk's LDS reads done
    // stage A tile [MT][64]
    #pragma unroll
    for (int ii = 0; ii < AI; ++ii) {
      int i = w * AI + ii;
      int f = i * 64 + lane;                 // 16B slot index
      int m = f >> 3, s = f & 7;
      int ko = s ^ (m & 7);                  // which global k-octet goes here
      const bf16* g = Asrc + (row0 + (size_t)m) * ldA + (size_t)(k0e + ko * 8);
      async16(g, smem + i * 1024);
    }
    // stage B tile [256 n][64 k] = 32 issues (8 per wave)
    #pragma unroll
    for (int ii = 0; ii < 8; ++ii) {
      int i = w * 8 + ii;
      int f = i * 64 + lane;
      int n = f >> 3, s = f & 7;
      int ko = s ^ (n & 7);
      const bf16* g = B + (size_t)(ncol0 + n) * KTOT + (size_t)(k0 + ko * 8);
      async16(g, smem + 16384 + i * 1024);
    }
    __syncthreads();                         // drains vmcnt before barrier

    #pragma unroll
    for (int ks = 0; ks < 2; ++ks) {
      bf16x8 av[MI]; bf16x8 bv[4];
      const int ko = q + 4 * ks;             // operand: k = ko*8 + j
      #pragma unroll
      for (int mi = 0; mi < MI; ++mi) {      // A: m = lane&15, k = quad*8+j
        int m = 16 * mi + t16;
        int f = m * 8 + (ko ^ (m & 7));
        av[mi] = *(const bf16x8*)(smem + f * 16);
      }
      #pragma unroll
      for (int ni = 0; ni < 4; ++ni) {       // B: n = lane&15, k = quad*8+j
        int n = 64 * w + 16 * ni + t16;
        int f = n * 8 + (ko ^ (n & 7));
        bv[ni] = *(const bf16x8*)(smem + 16384 + f * 16);
      }
      #pragma unroll
      for (int mi = 0; mi < MI; ++mi)
        #pragma unroll
        for (int ni = 0; ni < 4; ++ni)
          acc[mi][ni] = __builtin_amdgcn_mfma_f32_16x16x32_bf16(
              av[mi], bv[ni], acc[mi][ni], 0, 0, 0);
    }
  }

  // ---- epilogue via LDS transpose bridge ----
  // MFMA C/D layout: col = lane&15, row = quad*4 + reg  [m89-verified]
  float* lds_f = (float*)smem;               // [16][LDSF_STRIDE] chunk
  #pragma unroll
  for (int mi = 0; mi < MI; ++mi) {
    __syncthreads();                         // prev chunk consumed / K-loop reads done
    #pragma unroll
    for (int ni = 0; ni < 4; ++ni)
      #pragma unroll
      for (int r = 0; r < 4; ++r)
        lds_f[(4 * q + r) * LDSF_STRIDE + 64 * w + 16 * ni + t16] = acc[mi][ni][r];
    __syncthreads();
    #pragma unroll
    for (int j = 0; j < 2; ++j) {
      int task = tid + 256 * j;              // 512 tasks: 16 rows x 32 col-octets
      int rr = task >> 5, cg = task & 31;
      int c0 = cg * 8;
      size_t rg = row0 + 16 * mi + rr;
      f32x4 v0 = *(const f32x4*)(lds_f + rr * LDSF_STRIDE + c0);
      f32x4 v1 = *(const f32x4*)(lds_f + rr * LDSF_STRIDE + c0 + 4);
      float v[8] = {v0[0], v0[1], v0[2], v0[3], v1[0], v1[1], v1[2], v1[3]};
      if constexpr (EPI == 0) {
        bf16x8 o;
        #pragma unroll
        for (int k = 0; k < 8; ++k) o[k] = f2bf(v[k]);
        *(bf16x8*)(Obf + rg * ldOut + (ncol0 + c0)) = o;
      } else if constexpr (EPI == 2) {
        bf16x8 o;
        #pragma unroll
        for (int k = 0; k < 8; ++k) o[k] = f2bf(fmaxf(v[k] + s_bias[c0 + k], 0.f));
        *(bf16x8*)(Obf + rg * 256 + c0) = o;
      } else {  // EPI == 4: h_new = 2*h + (acc + bias)
        f32x4 h0 = *(const f32x4*)(Hf + rg * 256 + c0);
        f32x4 h1 = *(const f32x4*)(Hf + rg * 256 + c0 + 4);
        float hh[8] = {h0[0], h0[1], h0[2], h0[3], h1[0], h1[1], h1[2], h1[3]};
        bf16x8 o; f32x4 n0, n1;
        #pragma unroll
        for (int k = 0; k < 8; ++k) {
          float hn = 2.f * hh[k] + v[k] + s_bias[c0 + k];
          o[k] = f2bf(hn);
          if (k < 4) n0[k] = hn; else n1[k - 4] = hn;
        }
        *(f32x4*)(Hf + rg * 256 + c0)     = n0;
        *(f32x4*)(Hf + rg * 256 + c0 + 4) = n1;
        *(bf16x8*)(Hbf + rg * 256 + c0) = o;
      }
    }
  }
}

// ---------------------------------------------------------------------------
// FULLY FUSED edge pipeline: block = 80 edges = exactly 4 nodes.
//   m1 = relu(gauss(dist) @ Wg + P_r[row] + P_c[col] + rad*wrad + be1)
//   agg = segment_sum(relu(m1 @ We2 + be2))
// m1 lives only in LDS (never HBM): saves ~330 MB HBM traffic per layer.
// Phase 1: GEMM1 K=64 with the Gaussian A-fragment computed IN REGISTERS.
// Phase 2: wave-private bridge -> coalesced Prc gathers -> relu -> ds_write
//          into LDS m1 tile [80][256] bf16 (pitch 512 B, octet^row swizzle).
// Phase 3: GEMM2 K=256 (A from LDS m1, We2 staged in 64-chunks).
// Phase 4: register relu+segsum (4|20: each f32x4 group is in ONE node),
//          shfl_xor butterfly over quad bits, write Agg only.
// ---------------------------------------------------------------------------
#define M1OFF 0            // m1 tile: 80 rows x 512 B = 40960
#define BREG  40960        // B region: 32 KB (WgT, wave bridges, We2 chunks)
__global__ void __launch_bounds__(256, 2)
edge_fused(const bf16* WgT_l, const bf16* We2T_l, const float* off,
           const float* pos, const int* eidx, const bf16* Prc,
           const float* be1, const float* wrad, const float* be2, bf16* Agg)
{
  __shared__ __align__(16) char smem[73728];   // m1 40960 + B 32768
  __shared__ int   s_erow[80];
  __shared__ int   s_ecol[80];
  __shared__ float s_rad[80];
  __shared__ float s_dist[80];
  __shared__ float s_b1[256];
  __shared__ float s_wrad[256];
  __shared__ float s_b2[256];
  __shared__ float s_off[64];

  const int tid  = threadIdx.x;
  const int w    = tid >> 6;
  const int lane = tid & 63;
  const int q    = lane >> 4;
  const int t16  = lane & 15;
  const size_t erow0 = (size_t)blockIdx.x * 80;

  if (tid < 80) {
    int e = (int)erow0 + tid;
    int r = eidx[e], c = eidx[ETOT + e];
    float dx = pos[c * 3 + 0] - pos[r * 3 + 0];
    float dy = pos[c * 3 + 1] - pos[r * 3 + 1];
    float dz = pos[c * 3 + 2] - pos[r * 3 + 2];
    float d2 = dx * dx + dy * dy + dz * dz;
    s_erow[tid] = r; s_ecol[tid] = c;
    s_rad[tid]  = 0.01f * d2;                // (ANG_TO_NM)^2 * |dvec|^2
    s_dist[tid] = sqrtf(d2);
  }
  if (tid < 64) s_off[tid] = off[tid];
  s_b1[tid]   = be1[tid];
  s_wrad[tid] = wrad[tid];
  s_b2[tid]   = be2[tid];

  // stage WgT B tile [256 n][64 k] into B region via async DMA
  #pragma unroll
  for (int ii = 0; ii < 8; ++ii) {
    int i = w * 8 + ii;
    int f = i * 64 + lane;
    int n = f >> 3, s = f & 7;
    int ko = s ^ (n & 7);
    async16(WgT_l + (size_t)n * 64 + ko * 8, smem + BREG + i * 1024);
  }
  __syncthreads();                           // drains DMA; s_* visible

  // ---- Phase 1: GEMM1, Gaussian A in registers ----
  // A[m][k]: m = 16mi + t16, k = (q + 4ks)*8 + j
  const float GC = -0.5f / ((5.0f / 63.0f) * (5.0f / 63.0f));
  float offk[2][8];
  #pragma unroll
  for (int ks = 0; ks < 2; ++ks)
    #pragma unroll
    for (int j = 0; j < 8; ++j) offk[ks][j] = s_off[(q + 4 * ks) * 8 + j];

  bf16x8 ag[5][2];
  #pragma unroll
  for (int mi = 0; mi < 5; ++mi) {
    float d = s_dist[16 * mi + t16];
    #pragma unroll
    for (int ks = 0; ks < 2; ++ks)
      #pragma unroll
      for (int j = 0; j < 8; ++j) {
        float t = d - offk[ks][j];
        ag[mi][ks][j] = f2bf(__expf(GC * t * t));
      }
  }

  f32x4 acc1[5][4] = {};
  #pragma unroll
  for (int ks = 0; ks < 2; ++ks) {
    bf16x8 bv[4];
    const int ko = q + 4 * ks;
    #pragma unroll
    for (int ni = 0; ni < 4; ++ni) {
      int n = 64 * w + 16 * ni + t16;
      int f = n * 8 + (ko ^ (n & 7));
      bv[ni] = *(const bf16x8*)(smem + BREG + f * 16);
    }
    #pragma unroll
    for (int mi = 0; mi < 5; ++mi)
      #pragma unroll
      for (int ni = 0; ni < 4; ++ni)
        acc1[mi][ni] = __builtin_amdgcn_mfma_f32_16x16x32_bf16(
            ag[mi][ks], bv[ni], acc1[mi][ni], 0, 0, 0);
  }

  // ---- Phase 2: wave-private bridge -> Prc epilogue -> LDS m1 tile ----
  // Wave w bridges inside its OWN B slice (bytes BREG+8192w..), which no
  // other wave reads -> no barrier needed (wave64 lockstep orders LDS ops).
  {
    float* br = (float*)(smem + BREG + 8192 * w);   // [16][WBR_STRIDE]
    const int rs = lane >> 3, oct = lane & 7;
    const int c0e = 64 * w + oct * 8;
    float b18[8], wr8[8];
    #pragma unroll
    for (int k = 0; k < 8; ++k) { b18[k] = s_b1[c0e + k]; wr8[k] = s_wrad[c0e + k]; }

    #pragma unroll
    for (int mi = 0; mi < 5; ++mi) {
      #pragma unroll
      for (int ni = 0; ni < 4; ++ni)
        #pragma unroll
        for (int r = 0; r < 4; ++r)
          br[(4 * q + r) * WBR_STRIDE + 16 * ni + t16] = acc1[mi][ni][r];
      #pragma unroll
      for (int pass = 0; pass < 2; ++pass) {
        int rr = pass * 8 + rs;
        int rl = 16 * mi + rr;               // local edge row 0..79
        int er = s_erow[rl], ec = s_ecol[rl];
        float rad = s_rad[rl];
        bf16x8 pr = *(const bf16x8*)(Prc + (size_t)er * 512 + c0e);
        bf16x8 pc = *(const bf16x8*)(Prc + (size_t)ec * 512 + 256 + c0e);
        float v[8];
        #pragma unroll
        for (int jj = 0; jj < 4; ++jj) {
          float2 t = *(const float2*)(br + rr * WBR_STRIDE + oct * 8 + 2 * jj);
          v[2 * jj] = t.x; v[2 * jj + 1] = t.y;
        }
        bf16x8 o;
        #pragma unroll
        for (int k = 0; k < 8; ++k) {
          float val = v[k] + b18[k] + rad * wr8[k] + bf2f(pr[k]) + bf2f(pc[k]);
          o[k] = f2bf(fmaxf(val, 0.f));
        }
        // m1 tile: row rl, k-octet (8w+oct), swizzled by row&7
        int od = (8 * w + oct) ^ (rl & 7);
        *(bf16x8*)(smem + rl * 512 + od * 16) = o;
      }
    }
  }
  __syncthreads();                           // m1 tile complete

  // ---- Phase 3: GEMM2 (K=256), A = LDS m1 tile, B = We2 chunks ----
  f32x4 acc2[5][4] = {};
  for (int kc = 0; kc < 4; ++kc) {
    if (kc) __syncthreads();                 // prev chunk's B reads done
    #pragma unroll
    for (int ii = 0; ii < 8; ++ii) {
      int i = w * 8 + ii;
      int f = i * 64 + lane;
      int n = f >> 3, s = f & 7;
      int ko = s ^ (n & 7);
      async16(We2T_l + (size_t)n * 256 + (size_t)(64 * kc + ko * 8),
              smem + BREG + i * 1024);
    }
    __syncthreads();

    #pragma unroll
    for (int ks = 0; ks < 2; ++ks) {
      bf16x8 av[5]; bf16x8 bv[4];
      const int ko = q + 4 * ks;
      #pragma unroll
      for (int mi = 0; mi < 5; ++mi) {
        int m = 16 * mi + t16;
        int oa = (8 * kc + ko) ^ (t16 & 7);  // (m&7) == (t16&7)
        av[mi] = *(const bf16x8*)(smem + m * 512 + oa * 16);
      }
      #pragma unroll
      for (int ni = 0; ni < 4; ++ni) {
        int n = 64 * w + 16 * ni + t16;
        int f = n * 8 + (ko ^ (n & 7));
        bv[ni] = *(const bf16x8*)(smem + BREG + f * 16);
      }
      #pragma unroll
      for (int mi = 0; mi < 5; ++mi)
        #pragma unroll
        for (int ni = 0; ni < 4; ++ni)
          acc2[mi][ni] = __builtin_amdgcn_mfma_f32_16x16x32_bf16(
              av[mi], bv[ni], acc2[mi][ni], 0, 0, 0);
    }
  }

  // ---- Phase 4: register relu + segment-sum (no LDS, no barriers) ----
  #pragma unroll
  for (int ni = 0; ni < 4; ++ni) {
    float b = s_b2[64 * w + 16 * ni + t16];
    float pp[5];
    #pragma unroll
    for (int mi = 0; mi < 5; ++mi) {
      float s = 0.f;
      #pragma unroll
      for (int r = 0; r < 4; ++r) s += fmaxf(acc2[mi][ni][r] + b, 0.f);
      pp[mi] = s;
    }
    #pragma unroll
    for (int nn = 0; nn < 4; ++nn) {        // node nn: groups g in [5nn, 5nn+4]
      float s = 0.f;
      #pragma unroll
      for (int mi = 0; mi < 5; ++mi) {
        int g = 4 * mi + q;
        if (g >= 5 * nn && g <= 5 * nn + 4) s += pp[mi];
      }
      s += __shfl_xor(s, 16, 64);           // reduce over quad bit 0
      s += __shfl_xor(s, 32, 64);           // reduce over quad bit 1
      if (q == nn)
        Agg[((size_t)blockIdx.x * 4 + nn) * 256 + 64 * w + 16 * ni + t16] =
            __float2bfloat16(s);
    }
  }
}

// ---------------------------------------------------------------------------
// Prep kernels: weight repack/transpose to bf16 [n][k] layouts, once per call
// ---------------------------------------------------------------------------
__global__ void wrct_kernel(const float* We1, bf16* WrcT) {
  int idx = blockIdx.x * 256 + threadIdx.x;         // L*512*256
  int k = idx & 255, np = (idx >> 8) & 511, l = idx >> 17;
  float v = (np < 256)
      ? We1[((size_t)l * 577 + k) * 256 + np]
      : We1[((size_t)l * 577 + 256 + k) * 256 + (np - 256)];
  WrcT[idx] = __float2bfloat16(v);
}
__global__ void wgt_kernel(const float* We1, bf16* WgT) {
  int idx = blockIdx.x * 256 + threadIdx.x;         // L*256*64
  int k = idx & 63, n = (idx >> 6) & 255, l = idx >> 14;
  WgT[idx] = __float2bfloat16(We1[((size_t)l * 577 + 513 + k) * 256 + n]);
}
__global__ void wrad_kernel(const float* We1, float* wrad) {
  int idx = blockIdx.x * 256 + threadIdx.x;         // L*256
  int n = idx & 255, l = idx >> 8;
  wrad[idx] = We1[((size_t)l * 577 + 512) * 256 + n];
}
__global__ void trans_kernel(const float* src, bf16* dst, int R, int C) {
  int idx = blockIdx.x * 256 + threadIdx.x;         // L*C*R, dst [l][n][k]
  int k = idx % R, rest = idx / R;
  int n = rest % C, l = rest / C;
  dst[idx] = __float2bfloat16(src[((size_t)l * R + k) * C + n]);
}

__global__ void h0_kernel(const int* types, const float* emb, float* h, bf16* hbf) {
  int i = blockIdx.x, c = threadIdx.x;
  float v = emb[(size_t)(types[i] - 1) * 256 + c];
  h[(size_t)i * 256 + c] = v;
  hbf[(size_t)i * 256 + c] = __float2bfloat16(v);
}

// global mean pool over 32 atoms per building block
__global__ void pool_kernel(const float* h, float* out) {
  int b = blockIdx.x, c = threadIdx.x;
  float s = 0.f;
  #pragma unroll
  for (int j = 0; j < 32; ++j) s += h[((size_t)b * 32 + j) * 256 + c];
  out[(size_t)b * 256 + c] = s * (1.0f / 32.0f);
}

// ---------------------------------------------------------------------------
extern "C" void kernel_launch(void* const* d_in, const int* in_sizes, int n_in,
                              void* d_out, int out_size, void* d_ws, size_t ws_size,
                              hipStream_t stream) {
  const float* pos   = (const float*)d_in[0];
  const int*   atype = (const int*)  d_in[1];
  const int*   eidx  = (const int*)  d_in[2];
  const float* emb   = (const float*)d_in[4];
  const float* off   = (const float*)d_in[5];
  const float* We1   = (const float*)d_in[6];
  const float* be1   = (const float*)d_in[7];
  const float* We2   = (const float*)d_in[8];
  const float* be2   = (const float*)d_in[9];
  const float* Wn1   = (const float*)d_in[10];
  const float* bn1   = (const float*)d_in[11];
  const float* Wn2   = (const float*)d_in[12];
  const float* bn2   = (const float*)d_in[13];
  float* out = (float*)d_out;

  // ---- workspace carve (256B aligned, ~61 MB total; ws_size = 256 MiB) ----
  size_t o = 0;
  auto carve = [&](size_t bytes) {
    void* p = (char*)d_ws + o;
    o += (bytes + 255) & ~(size_t)255;
    return p;
  };
  float* h     = (float*)carve((size_t)NATOMS * 256 * 4);   // 16 MB
  bf16*  hbf   = (bf16*) carve((size_t)NATOMS * 256 * 2);   //  8 MB
  bf16*  Prc   = (bf16*) carve((size_t)NATOMS * 512 * 2);   // 16 MB
  bf16*  aggbf = (bf16*) carve((size_t)NATOMS * 256 * 2);   //  8 MB (agg, then nMLP1 out)
  bf16*  WrcT  = (bf16*) carve((size_t)NLAYER * 512 * 256 * 2);
  bf16*  WgT   = (bf16*) carve((size_t)NLAYER * 256 * 64 * 2);
  bf16*  We2T  = (bf16*) carve((size_t)NLAYER * 256 * 256 * 2);
  bf16*  Wn1T  = (bf16*) carve((size_t)NLAYER * 256 * 512 * 2);
  bf16*  Wn2T  = (bf16*) carve((size_t)NLAYER * 256 * 256 * 2);
  float* wradp = (float*)carve((size_t)NLAYER * 256 * 4);

  // ---- prep: weights -> bf16 transposed, h0 gather ----
  wrct_kernel<<<2048, 256, 0, stream>>>(We1, WrcT);
  wgt_kernel <<< 256, 256, 0, stream>>>(We1, WgT);
  wrad_kernel<<<   4, 256, 0, stream>>>(We1, wradp);
  trans_kernel<<<1024, 256, 0, stream>>>(We2, We2T, 256, 256);
  trans_kernel<<<2048, 256, 0, stream>>>(Wn1, Wn1T, 512, 256);
  trans_kernel<<<1024, 256, 0, stream>>>(Wn2, Wn2T, 256, 256);
  h0_kernel  <<<NATOMS, 256, 0, stream>>>(atype, emb, h, hbf);

  // ---- layers ----
  for (int l = 0; l < NLAYER; ++l) {
    // Prc[N,512] = h @ [We1_r | We1_c]
    gemm_k<256, 0, 64><<<dim3(256, 2), 256, 0, stream>>>(
        hbf, nullptr, WrcT + (size_t)l * 512 * 256, Prc, 512, nullptr,
        nullptr, nullptr);
    // agg = segment_sum(relu(MLP2(MLP1(edges)))) — m1 never leaves LDS
    edge_fused<<<ETOT / 80, 256, 0, stream>>>(
        WgT + (size_t)l * 256 * 64, We2T + (size_t)l * 256 * 256, off, pos,
        eidx, Prc, be1 + l * 256, wradp + l * 256, be2 + l * 256, aggbf);
    // t[N,256] = relu([h|agg] @ Wn1 + bn1), in-place into aggbf
    gemm_k<512, 2, 64><<<dim3(256, 1), 256, 0, stream>>>(
        hbf, aggbf, Wn1T + (size_t)l * 256 * 512, aggbf, 256, bn1 + l * 256,
        nullptr, nullptr);
    // h = 2h + (t @ Wn2 + bn2)
    gemm_k<256, 4, 64><<<dim3(256, 1), 256, 0, stream>>>(
        aggbf, nullptr, Wn2T + (size_t)l * 256 * 256, nullptr, 0, bn2 + l * 256,
        h, hbf);
  }

  pool_kernel<<<512, 256, 0, stream>>>(h, out);
}